// Round 7
// baseline (390.310 us; speedup 1.0000x reference)
//
#include <hip/hip_runtime.h>
#include <math.h>

#define N_NODES 4096
#define IN_DIM  512
#define H_DIM   256
#define OUT_DIM 64
#define SCAD_Af 3.7f
#define EPSf    1e-8f
#define NBINS   8192      // 32 KB LDS hist; bin width 2.44e-4 (quantile err << tol)
#define MAXD    256       // padded CSR stride (max degree ~105 stochastically)
#define KSPLIT  4

__device__ __forceinline__ float scad_w(float y, float lamc) {
    if (y <= lamc) return 1.0f;
    if (y <= SCAD_Af * lamc)
        return (SCAD_Af * lamc - y) / ((SCAD_Af - 1.0f) * fmaxf(y, EPSf));
    return 0.0f;
}

// ---------------------------------------------------------------------------
// k_init, grid 2048x256:
//   blocks [0,1024):     gemm1 K-split partials (4 x 64 x 4 tiles linearized)
//   blocks [1024,2048):  degfill (4 rows/block, wave-per-row, padded CSR)
//                        + zero both histogram buffers
__global__ __launch_bounds__(256)
void k_init(const float* __restrict__ A, const float* __restrict__ X,
            const float* __restrict__ W1, float* __restrict__ part,
            int* __restrict__ colIdx, int* __restrict__ rowcnt,
            float* __restrict__ D, float* __restrict__ isD,
            unsigned int* __restrict__ hist01) {
    __shared__ float As[16][68];
    __shared__ float Bs[16][64];
    __shared__ int cnt4[4];
    int tid = threadIdx.x;
    if (blockIdx.x < 1024) {
        int blk = blockIdx.x;
        int bx = blk & 3, by = (blk >> 2) & 63, bz = blk >> 8;
        int tx = tid & 15, ty = tid >> 4;
        int bm = by * 64, bn = bx * 64;
        int kbeg = bz * (IN_DIM / KSPLIT);
        float acc[4][4] = {};
        for (int k0 = kbeg; k0 < kbeg + IN_DIM / KSPLIT; k0 += 16) {
            {
                int r = tid >> 2, kv = tid & 3;
                float4 v = *(const float4*)(X + (size_t)(bm + r) * IN_DIM + k0 + kv * 4);
                As[kv * 4 + 0][r] = v.x;
                As[kv * 4 + 1][r] = v.y;
                As[kv * 4 + 2][r] = v.z;
                As[kv * 4 + 3][r] = v.w;
            }
            {
                int kk = tid >> 4, nv = tid & 15;
                *(float4*)&Bs[kk][nv * 4] =
                    *(const float4*)(W1 + (size_t)(k0 + kk) * H_DIM + bn + nv * 4);
            }
            __syncthreads();
#pragma unroll
            for (int kk = 0; kk < 16; kk++) {
                float a[4], b[4];
#pragma unroll
                for (int u = 0; u < 4; u++) { a[u] = As[kk][ty * 4 + u]; b[u] = Bs[kk][tx * 4 + u]; }
#pragma unroll
                for (int u = 0; u < 4; u++)
#pragma unroll
                    for (int v = 0; v < 4; v++) acc[u][v] += a[u] * b[v];
            }
            __syncthreads();
        }
        float* Cm = part + (size_t)bz * N_NODES * H_DIM;
#pragma unroll
        for (int u = 0; u < 4; u++) {
            int m = bm + ty * 4 + u;
#pragma unroll
            for (int v = 0; v < 4; v++)
                Cm[(size_t)m * H_DIM + bn + tx * 4 + v] = acc[u][v];
        }
    } else {
        int bb = blockIdx.x - 1024;
        int gid2 = bb * 256 + tid;
        if (gid2 < 2 * NBINS) hist01[gid2] = 0u;   // zero both hist buffers
        int w = tid >> 6, lane = tid & 63;
        int i = bb * 4 + w;
        if (lane == 0) cnt4[w] = 0;
        __syncthreads();
        const float* row = A + (size_t)i * N_NODES;
        for (int j = lane; j < N_NODES; j += 64) {
            if (row[j] != 0.0f) {
                int p = atomicAdd(&cnt4[w], 1);   // LDS atomic, per-wave counter
                colIdx[i * MAXD + p] = j;
            }
        }
        __syncthreads();
        if (lane == 0) {
            int t = cnt4[w];
            rowcnt[i] = t;
            float d = (float)t + 1.0f;   // add_loops
            D[i] = d;
            isD[i] = 1.0f / sqrtf(d);
        }
    }
}

// ---------------------------------------------------------------------------
// k_mlp2, grid 1024x256: F0[i,c] = relu(X@W1+b1)[i,:] @ W2[:,c] + b2[c],
// with H1 row i built in registers from the K-split partials (each row read by
// exactly one wave). Also emits Fu0 (row-local norm) and nE (block 0).
__global__ __launch_bounds__(256)
void k_mlp2(const float* __restrict__ part, const float* __restrict__ b1,
            const float* __restrict__ W2, const float* __restrict__ b2,
            const int* __restrict__ rowcnt, const float* __restrict__ isD,
            float* __restrict__ F0, float* __restrict__ Fu, int* __restrict__ nE) {
    int tid = threadIdx.x;
    if (blockIdx.x == 0) {
        __shared__ unsigned int ps[256];
        unsigned int s = 0;
        for (int q = tid; q < N_NODES; q += 256) s += (unsigned int)rowcnt[q];
        ps[tid] = s;
        __syncthreads();
        for (int off = 128; off; off >>= 1) {
            if (tid < off) ps[tid] += ps[tid + off];
            __syncthreads();
        }
        if (tid == 0) nE[0] = (int)ps[0];
    }
    int gid = blockIdx.x * 256 + tid;
    int i = gid >> 6, c = gid & 63;
    const size_t tot = (size_t)N_NODES * H_DIM / 4;
    const float4* p0 = (const float4*)part + (size_t)i * (H_DIM / 4);
    const float4* p1 = p0 + tot;
    const float4* p2 = p1 + tot;
    const float4* p3 = p2 + tot;
    const float4* b14 = (const float4*)b1;
    float a0 = 0, a1 = 0, a2 = 0, a3 = 0;
    for (int k4 = 0; k4 < H_DIM / 4; k4++) {
        float4 q0 = p0[k4], q1 = p1[k4], q2 = p2[k4], q3 = p3[k4], bb = b14[k4];
        float h0 = fmaxf(q0.x + q1.x + q2.x + q3.x + bb.x, 0.0f);
        float h1 = fmaxf(q0.y + q1.y + q2.y + q3.y + bb.y, 0.0f);
        float h2 = fmaxf(q0.z + q1.z + q2.z + q3.z + bb.z, 0.0f);
        float h3 = fmaxf(q0.w + q1.w + q2.w + q3.w + bb.w, 0.0f);
        a0 += h0 * W2[(k4 * 4 + 0) * OUT_DIM + c];
        a1 += h1 * W2[(k4 * 4 + 1) * OUT_DIM + c];
        a2 += h2 * W2[(k4 * 4 + 2) * OUT_DIM + c];
        a3 += h3 * W2[(k4 * 4 + 3) * OUT_DIM + c];
    }
    float f0 = (a0 + a1) + (a2 + a3) + b2[c];
    F0[(size_t)i * 64 + c] = f0;
    // fused row-local normalize
    float fn = f0 * isD[i];
    float s2 = fn * fn;
    for (int off = 32; off; off >>= 1) s2 += __shfl_xor(s2, off, 64);
    Fu[(size_t)i * 64 + c] = fn / fmaxf(sqrtf(s2), EPSf);
}

// ---------------------------------------------------------------------------
// Edge cosine distances + LDS hist. Wave per row, 16 edges in flight.
__global__ __launch_bounds__(256)
void k_edgehist(const float* __restrict__ Fu, const int* __restrict__ rowcnt,
                const int* __restrict__ colIdx, float* __restrict__ y_e,
                unsigned int* __restrict__ histK) {
    __shared__ unsigned int hl[NBINS];
    for (int b = threadIdx.x; b < NBINS; b += 256) hl[b] = 0u;
    __syncthreads();
    int gid = blockIdx.x * 256 + threadIdx.x;
    int ri = gid >> 6;
    int lane = threadIdx.x & 63;
    int eg = lane >> 2, el = lane & 3;
    int deg = rowcnt[ri];
    const float4* Fu4 = (const float4*)Fu;
    float4 fi0 = Fu4[ri * 16 + el * 4 + 0];
    float4 fi1 = Fu4[ri * 16 + el * 4 + 1];
    float4 fi2 = Fu4[ri * 16 + el * 4 + 2];
    float4 fi3 = Fu4[ri * 16 + el * 4 + 3];
    for (int base = 0; base < deg; base += 16) {
        int e = base + eg;
        bool act = e < deg;
        int j = act ? colIdx[ri * MAXD + e] : ri;
        float4 a0 = Fu4[(size_t)j * 16 + el * 4 + 0];
        float4 a1 = Fu4[(size_t)j * 16 + el * 4 + 1];
        float4 a2 = Fu4[(size_t)j * 16 + el * 4 + 2];
        float4 a3 = Fu4[(size_t)j * 16 + el * 4 + 3];
        float s = fi0.x * a0.x + fi0.y * a0.y + fi0.z * a0.z + fi0.w * a0.w
                + fi1.x * a1.x + fi1.y * a1.y + fi1.z * a1.z + fi1.w * a1.w
                + fi2.x * a2.x + fi2.y * a2.y + fi2.z * a2.z + fi2.w * a2.w
                + fi3.x * a3.x + fi3.y * a3.y + fi3.z * a3.z + fi3.w * a3.w;
        s += __shfl_xor(s, 1, 64);
        s += __shfl_xor(s, 2, 64);
        if (act && el == 0) {
            float y = 1.0f - s;
            y = fminf(fmaxf(y, 0.0f), 2.0f);
            y_e[ri * MAXD + e] = y;
            int bin = (int)(y * (NBINS * 0.5f));
            if (bin > NBINS - 1) bin = NBINS - 1;
            atomicAdd(&hl[bin], 1u);
        }
    }
    __syncthreads();
    for (int b = threadIdx.x; b < NBINS; b += 256) {
        unsigned int v = hl[b];
        if (v) atomicAdd(&histK[b], v);   // sparse device-atomic flush
    }
}

// ---------------------------------------------------------------------------
// Quantile (per-block redundant scan of histK) + propagation + fused norm of
// the produced row + zero histNext (double buffer for next iteration).
__global__ __launch_bounds__(256)
void k_propq(const unsigned int* __restrict__ histK, unsigned int* __restrict__ histNext,
             const int* __restrict__ nEp, const int* __restrict__ rowcnt,
             const int* __restrict__ colIdx, const float* __restrict__ y_e,
             const float* __restrict__ Fc, const float* __restrict__ F0,
             const float* __restrict__ D, const float* __restrict__ isD,
             const float* __restrict__ lg0, const float* __restrict__ rdec,
             const float* __restrict__ ralpha, int kiter,
             float* __restrict__ Fout, float* __restrict__ FuNext) {
    __shared__ unsigned int psum[256];
    __shared__ float vv[2];
    __shared__ float sh_scal;
    int tid = threadIdx.x;
    int gid = blockIdx.x * 256 + tid;
    if (gid < NBINS) histNext[gid] = 0u;   // zero the other buffer for next iter
    {   // ---- quantile phase ----
        unsigned int cnt[32];
        const uint4* h4 = (const uint4*)histK;
        unsigned int s = 0;
#pragma unroll
        for (int q = 0; q < 8; q++) {
            uint4 v = h4[tid * 8 + q];
            cnt[q * 4 + 0] = v.x; cnt[q * 4 + 1] = v.y;
            cnt[q * 4 + 2] = v.z; cnt[q * 4 + 3] = v.w;
            s += v.x + v.y + v.z + v.w;
        }
        psum[tid] = s;
        __syncthreads();
        for (int off = 1; off < 256; off <<= 1) {
            unsigned int x = 0;
            if (tid >= off) x = psum[tid - off];
            __syncthreads();
            psum[tid] += x;
            __syncthreads();
        }
        int nE = nEp[0];
        double h = 0.75 * (double)(nE - 1);
        long long i0 = (long long)h;
        float frac = (float)(h - (double)i0);
        unsigned int r0 = (unsigned int)i0, r1 = (unsigned int)(i0 + 1);
        unsigned int cum = (tid == 0) ? 0u : psum[tid - 1];
#pragma unroll
        for (int b = 0; b < 32; b++) {
            unsigned int cn = cnt[b];
            unsigned int lo = cum;
            cum += cn;
            if (cn) {
                float v = ((float)(tid * 32 + b) + 0.5f) * (2.0f / (float)NBINS);
                if (lo <= r0 && r0 < cum) vv[0] = v;
                if (lo <= r1 && r1 < cum) vv[1] = v;
            }
        }
        __syncthreads();
        if (tid == 0) {
            float gd = vv[0] + frac * (vv[1] - vv[0]);
            gd = fmaxf(gd, EPSf);
            float alpha = 1.0f / (1.0f + expf(-ralpha[0]));
            float g0 = expf(lg0[0]);
            float r = 1.0f / (1.0f + expf(-rdec[0]));
            float gp = g0;
            for (int q = 0; q < kiter; q++) gp *= r;
            sh_scal = alpha * (gp / SCAD_Af) + (1.0f - alpha) * (gd / SCAD_Af);
        }
        __syncthreads();
    }
    // ---- propagation phase: wave per row, lane = channel ----
    float lamc = sh_scal;
    const float lam = (float)(1.0 / 0.9 - 1.0);
    int i = gid >> 6, c = gid & 63;
    int deg = rowcnt[i];
    float acc = 0.0f, wsum = 0.0f;
    for (int base = 0; base < deg; base += 64) {
        int m = deg - base; if (m > 64) m = 64;
        int   jl = (c < m) ? colIdx[i * MAXD + base + c] : 0;
        float yl = (c < m) ? y_e[i * MAXD + base + c] : 9.0f;
        float il = (c < m) ? isD[jl] : 0.0f;
        int tt = 0;
        for (; tt + 4 <= m; tt += 4) {
            int j0 = __shfl(jl, tt, 64),     j1 = __shfl(jl, tt + 1, 64);
            int j2 = __shfl(jl, tt + 2, 64), j3 = __shfl(jl, tt + 3, 64);
            float f0 = Fc[(size_t)j0 * 64 + c], f1 = Fc[(size_t)j1 * 64 + c];
            float f2 = Fc[(size_t)j2 * 64 + c], f3 = Fc[(size_t)j3 * 64 + c];
            float s0 = scad_w(__shfl(yl, tt, 64),     lamc);
            float s1 = scad_w(__shfl(yl, tt + 1, 64), lamc);
            float s2 = scad_w(__shfl(yl, tt + 2, 64), lamc);
            float s3 = scad_w(__shfl(yl, tt + 3, 64), lamc);
            wsum += s0 + s1 + s2 + s3;
            acc += s0 * __shfl(il, tt, 64) * f0 + s1 * __shfl(il, tt + 1, 64) * f1
                 + s2 * __shfl(il, tt + 2, 64) * f2 + s3 * __shfl(il, tt + 3, 64) * f3;
        }
        for (; tt < m; tt++) {
            int   j = __shfl(jl, tt, 64);
            float y = __shfl(yl, tt, 64);
            float wq = scad_w(y, lamc);
            wsum += wq;
            acc += wq * __shfl(il, tt, 64) * Fc[(size_t)j * 64 + c];
        }
    }
    float Q = wsum / D[i] + lam;
    float fo = (isD[i] * acc + lam * F0[(size_t)i * 64 + c]) / Q;
    Fout[(size_t)i * 64 + c] = fo;
    // fused row-local normalize for the next iteration's edge phase
    float fn = fo * isD[i];
    float s2n = fn * fn;
    for (int off = 32; off; off >>= 1) s2n += __shfl_xor(s2n, off, 64);
    FuNext[(size_t)i * 64 + c] = fn / fmaxf(sqrtf(s2n), EPSf);
}

// ---------------------------------------------------------------------------
extern "C" void kernel_launch(void* const* d_in, const int* in_sizes, int n_in,
                              void* d_out, int out_size, void* d_ws, size_t ws_size,
                              hipStream_t stream) {
    const float* A      = (const float*)d_in[0];
    const float* X      = (const float*)d_in[1];
    const float* W1     = (const float*)d_in[2];
    const float* b1     = (const float*)d_in[3];
    const float* W2     = (const float*)d_in[4];
    const float* b2     = (const float*)d_in[5];
    const float* lg0    = (const float*)d_in[6];
    const float* rdec   = (const float*)d_in[7];
    const float* ralpha = (const float*)d_in[8];
    float* outp = (float*)d_out;

    char* w = (char*)d_ws;
    size_t off = 0;
    auto carve = [&](size_t bytes) -> char* {
        char* p = w + off;
        off += (bytes + 255) & ~(size_t)255;
        return p;
    };
    int*      colIdx = (int*)carve((size_t)N_NODES * MAXD * 4);       // 4 MB padded CSR
    float*    y_e    = (float*)carve((size_t)N_NODES * MAXD * 4);     // 4 MB padded
    float*    part   = (float*)carve((size_t)KSPLIT * N_NODES * H_DIM * 4); // 16 MB
    int*      rowcnt = (int*)carve(N_NODES * 4);
    float*    D      = (float*)carve(N_NODES * 4);
    float*    isD    = (float*)carve(N_NODES * 4);
    float*    Fu     = (float*)carve((size_t)N_NODES * 64 * 4);
    float*    F0     = (float*)carve((size_t)N_NODES * 64 * 4);
    float*    FcA    = (float*)carve((size_t)N_NODES * 64 * 4);
    float*    FcB    = (float*)carve((size_t)N_NODES * 64 * 4);
    unsigned* hist01 = (unsigned*)carve(2 * NBINS * 4);               // double buffer
    int*      nE     = (int*)carve(256);

    // 1: CSR build + gemm1 partials + hist zero (independent work, one launch)
    k_init<<<dim3(2048), dim3(256), 0, stream>>>(A, X, W1, part, colIdx, rowcnt, D, isD, hist01);
    // 2: F0 = relu(X@W1+b1)@W2+b2 (registers-only H1), Fu0, nE
    k_mlp2<<<dim3(1024), dim3(256), 0, stream>>>(part, b1, W2, b2, rowcnt, isD, F0, Fu, nE);

    const float* fin = F0;
    float* fouts[4] = {FcA, FcB, FcA, outp};
    for (int k = 0; k < 4; k++) {
        unsigned* histK    = hist01 + (k & 1) * NBINS;
        unsigned* histNext = hist01 + ((k + 1) & 1) * NBINS;
        k_edgehist<<<dim3(1024), dim3(256), 0, stream>>>(Fu, rowcnt, colIdx, y_e, histK);
        k_propq<<<dim3(1024), dim3(256), 0, stream>>>(histK, histNext, nE, rowcnt, colIdx,
                                                      y_e, fin, F0, D, isD, lg0, rdec,
                                                      ralpha, k, fouts[k], Fu);
        fin = fouts[k];
    }
}

// Round 8
// 368.649 us; speedup vs baseline: 1.0588x; 1.0588x over previous
//
#include <hip/hip_runtime.h>
#include <math.h>

#define N_NODES 4096
#define IN_DIM  512
#define H_DIM   256
#define OUT_DIM 64
#define SCAD_Af 3.7f
#define EPSf    1e-8f
#define NBINS   8192      // 32 KB LDS hist; bin width 2.44e-4 (quantile err << tol)
#define MAXD    256       // padded CSR stride (max degree ~105 stochastically)
#define KSPLIT  4

__device__ __forceinline__ float scad_w(float y, float lamc) {
    if (y <= lamc) return 1.0f;
    if (y <= SCAD_Af * lamc)
        return (SCAD_Af * lamc - y) / ((SCAD_Af - 1.0f) * fmaxf(y, EPSf));
    return 0.0f;
}

// ---------------------------------------------------------------------------
// k_init, grid 2048x256:
//   blocks [0,1024):     gemm1 K-split partials (4 x 64 x 4 tiles linearized)
//   blocks [1024,2048):  degfill (4 rows/block, wave-per-row, float4 A scan,
//                        padded CSR) + zero both histogram buffers
__global__ __launch_bounds__(256)
void k_init(const float* __restrict__ A, const float* __restrict__ X,
            const float* __restrict__ W1, float* __restrict__ part,
            int* __restrict__ colIdx, int* __restrict__ rowcnt,
            float* __restrict__ D, float* __restrict__ isD,
            unsigned int* __restrict__ hist01) {
    __shared__ float As[16][68];
    __shared__ float Bs[16][64];
    __shared__ int cnt4[4];
    int tid = threadIdx.x;
    if (blockIdx.x < 1024) {
        int blk = blockIdx.x;
        int bx = blk & 3, by = (blk >> 2) & 63, bz = blk >> 8;
        int tx = tid & 15, ty = tid >> 4;
        int bm = by * 64, bn = bx * 64;
        int kbeg = bz * (IN_DIM / KSPLIT);
        float acc[4][4] = {};
        for (int k0 = kbeg; k0 < kbeg + IN_DIM / KSPLIT; k0 += 16) {
            {
                int r = tid >> 2, kv = tid & 3;
                float4 v = *(const float4*)(X + (size_t)(bm + r) * IN_DIM + k0 + kv * 4);
                As[kv * 4 + 0][r] = v.x;
                As[kv * 4 + 1][r] = v.y;
                As[kv * 4 + 2][r] = v.z;
                As[kv * 4 + 3][r] = v.w;
            }
            {
                int kk = tid >> 4, nv = tid & 15;
                *(float4*)&Bs[kk][nv * 4] =
                    *(const float4*)(W1 + (size_t)(k0 + kk) * H_DIM + bn + nv * 4);
            }
            __syncthreads();
#pragma unroll
            for (int kk = 0; kk < 16; kk++) {
                float a[4], b[4];
#pragma unroll
                for (int u = 0; u < 4; u++) { a[u] = As[kk][ty * 4 + u]; b[u] = Bs[kk][tx * 4 + u]; }
#pragma unroll
                for (int u = 0; u < 4; u++)
#pragma unroll
                    for (int v = 0; v < 4; v++) acc[u][v] += a[u] * b[v];
            }
            __syncthreads();
        }
        float* Cm = part + (size_t)bz * N_NODES * H_DIM;
#pragma unroll
        for (int u = 0; u < 4; u++) {
            int m = bm + ty * 4 + u;
#pragma unroll
            for (int v = 0; v < 4; v++)
                Cm[(size_t)m * H_DIM + bn + tx * 4 + v] = acc[u][v];
        }
    } else {
        int bb = blockIdx.x - 1024;
        int gid2 = bb * 256 + tid;
        if (gid2 < 2 * NBINS) hist01[gid2] = 0u;   // zero both hist buffers
        int w = tid >> 6, lane = tid & 63;
        int i = bb * 4 + w;
        if (lane == 0) cnt4[w] = 0;
        __syncthreads();
        // float4 scan of row i: 16 B/lane, 1 KB/wave/instr, 16 iterations.
        const float4* row4 = (const float4*)(A + (size_t)i * N_NODES);
        int* ci = colIdx + i * MAXD;
        for (int v = lane; v < N_NODES / 4; v += 64) {
            float4 x = row4[v];
            int j0 = v * 4;
            if (x.x != 0.0f) { int p = atomicAdd(&cnt4[w], 1); ci[p] = j0; }
            if (x.y != 0.0f) { int p = atomicAdd(&cnt4[w], 1); ci[p] = j0 + 1; }
            if (x.z != 0.0f) { int p = atomicAdd(&cnt4[w], 1); ci[p] = j0 + 2; }
            if (x.w != 0.0f) { int p = atomicAdd(&cnt4[w], 1); ci[p] = j0 + 3; }
        }
        __syncthreads();
        if (lane == 0) {
            int t = cnt4[w];
            rowcnt[i] = t;
            float d = (float)t + 1.0f;   // add_loops
            D[i] = d;
            isD[i] = 1.0f / sqrtf(d);
        }
    }
}

// ---------------------------------------------------------------------------
// k_mlp2, grid 1024x256: F0[i,c] = relu(X@W1+b1)[i,:] @ W2[:,c] + b2[c],
// with H1 row i built in registers from the K-split partials (each row read by
// exactly one wave). Also emits Fu0 (row-local norm) and nE (block 0).
__global__ __launch_bounds__(256)
void k_mlp2(const float* __restrict__ part, const float* __restrict__ b1,
            const float* __restrict__ W2, const float* __restrict__ b2,
            const int* __restrict__ rowcnt, const float* __restrict__ isD,
            float* __restrict__ F0, float* __restrict__ Fu, int* __restrict__ nE) {
    int tid = threadIdx.x;
    if (blockIdx.x == 0) {
        __shared__ unsigned int ps[256];
        unsigned int s = 0;
        for (int q = tid; q < N_NODES; q += 256) s += (unsigned int)rowcnt[q];
        ps[tid] = s;
        __syncthreads();
        for (int off = 128; off; off >>= 1) {
            if (tid < off) ps[tid] += ps[tid + off];
            __syncthreads();
        }
        if (tid == 0) nE[0] = (int)ps[0];
    }
    int gid = blockIdx.x * 256 + tid;
    int i = gid >> 6, c = gid & 63;
    const size_t tot = (size_t)N_NODES * H_DIM / 4;
    const float4* p0 = (const float4*)part + (size_t)i * (H_DIM / 4);
    const float4* p1 = p0 + tot;
    const float4* p2 = p1 + tot;
    const float4* p3 = p2 + tot;
    const float4* b14 = (const float4*)b1;
    float a0 = 0, a1 = 0, a2 = 0, a3 = 0;
    for (int k4 = 0; k4 < H_DIM / 4; k4++) {
        float4 q0 = p0[k4], q1 = p1[k4], q2 = p2[k4], q3 = p3[k4], bb = b14[k4];
        float h0 = fmaxf(q0.x + q1.x + q2.x + q3.x + bb.x, 0.0f);
        float h1 = fmaxf(q0.y + q1.y + q2.y + q3.y + bb.y, 0.0f);
        float h2 = fmaxf(q0.z + q1.z + q2.z + q3.z + bb.z, 0.0f);
        float h3 = fmaxf(q0.w + q1.w + q2.w + q3.w + bb.w, 0.0f);
        a0 += h0 * W2[(k4 * 4 + 0) * OUT_DIM + c];
        a1 += h1 * W2[(k4 * 4 + 1) * OUT_DIM + c];
        a2 += h2 * W2[(k4 * 4 + 2) * OUT_DIM + c];
        a3 += h3 * W2[(k4 * 4 + 3) * OUT_DIM + c];
    }
    float f0 = (a0 + a1) + (a2 + a3) + b2[c];
    F0[(size_t)i * 64 + c] = f0;
    // fused row-local normalize
    float fn = f0 * isD[i];
    float s2 = fn * fn;
    for (int off = 32; off; off >>= 1) s2 += __shfl_xor(s2, off, 64);
    Fu[(size_t)i * 64 + c] = fn / fmaxf(sqrtf(s2), EPSf);
}

// ---------------------------------------------------------------------------
// Edge cosine distances + LDS hist. Wave per row, 16 edges in flight.
__global__ __launch_bounds__(256)
void k_edgehist(const float* __restrict__ Fu, const int* __restrict__ rowcnt,
                const int* __restrict__ colIdx, float* __restrict__ y_e,
                unsigned int* __restrict__ histK) {
    __shared__ unsigned int hl[NBINS];
    for (int b = threadIdx.x; b < NBINS; b += 256) hl[b] = 0u;
    __syncthreads();
    int gid = blockIdx.x * 256 + threadIdx.x;
    int ri = gid >> 6;
    int lane = threadIdx.x & 63;
    int eg = lane >> 2, el = lane & 3;
    int deg = rowcnt[ri];
    const float4* Fu4 = (const float4*)Fu;
    float4 fi0 = Fu4[ri * 16 + el * 4 + 0];
    float4 fi1 = Fu4[ri * 16 + el * 4 + 1];
    float4 fi2 = Fu4[ri * 16 + el * 4 + 2];
    float4 fi3 = Fu4[ri * 16 + el * 4 + 3];
    for (int base = 0; base < deg; base += 16) {
        int e = base + eg;
        bool act = e < deg;
        int j = act ? colIdx[ri * MAXD + e] : ri;
        float4 a0 = Fu4[(size_t)j * 16 + el * 4 + 0];
        float4 a1 = Fu4[(size_t)j * 16 + el * 4 + 1];
        float4 a2 = Fu4[(size_t)j * 16 + el * 4 + 2];
        float4 a3 = Fu4[(size_t)j * 16 + el * 4 + 3];
        float s = fi0.x * a0.x + fi0.y * a0.y + fi0.z * a0.z + fi0.w * a0.w
                + fi1.x * a1.x + fi1.y * a1.y + fi1.z * a1.z + fi1.w * a1.w
                + fi2.x * a2.x + fi2.y * a2.y + fi2.z * a2.z + fi2.w * a2.w
                + fi3.x * a3.x + fi3.y * a3.y + fi3.z * a3.z + fi3.w * a3.w;
        s += __shfl_xor(s, 1, 64);
        s += __shfl_xor(s, 2, 64);
        if (act && el == 0) {
            float y = 1.0f - s;
            y = fminf(fmaxf(y, 0.0f), 2.0f);
            y_e[ri * MAXD + e] = y;
            int bin = (int)(y * (NBINS * 0.5f));
            if (bin > NBINS - 1) bin = NBINS - 1;
            atomicAdd(&hl[bin], 1u);
        }
    }
    __syncthreads();
    for (int b = threadIdx.x; b < NBINS; b += 256) {
        unsigned int v = hl[b];
        if (v) atomicAdd(&histK[b], v);   // sparse device-atomic flush
    }
}

// ---------------------------------------------------------------------------
// Quantile (per-block redundant scan of histK) + propagation + fused norm of
// the produced row + zero histNext (double buffer for next iteration).
__global__ __launch_bounds__(256)
void k_propq(const unsigned int* __restrict__ histK, unsigned int* __restrict__ histNext,
             const int* __restrict__ nEp, const int* __restrict__ rowcnt,
             const int* __restrict__ colIdx, const float* __restrict__ y_e,
             const float* __restrict__ Fc, const float* __restrict__ F0,
             const float* __restrict__ D, const float* __restrict__ isD,
             const float* __restrict__ lg0, const float* __restrict__ rdec,
             const float* __restrict__ ralpha, int kiter,
             float* __restrict__ Fout, float* __restrict__ FuNext) {
    __shared__ unsigned int psum[256];
    __shared__ float vv[2];
    __shared__ float sh_scal;
    int tid = threadIdx.x;
    int gid = blockIdx.x * 256 + tid;
    if (gid < NBINS) histNext[gid] = 0u;   // zero the other buffer for next iter
    {   // ---- quantile phase ----
        unsigned int cnt[32];
        const uint4* h4 = (const uint4*)histK;
        unsigned int s = 0;
#pragma unroll
        for (int q = 0; q < 8; q++) {
            uint4 v = h4[tid * 8 + q];
            cnt[q * 4 + 0] = v.x; cnt[q * 4 + 1] = v.y;
            cnt[q * 4 + 2] = v.z; cnt[q * 4 + 3] = v.w;
            s += v.x + v.y + v.z + v.w;
        }
        psum[tid] = s;
        __syncthreads();
        for (int off = 1; off < 256; off <<= 1) {
            unsigned int x = 0;
            if (tid >= off) x = psum[tid - off];
            __syncthreads();
            psum[tid] += x;
            __syncthreads();
        }
        int nE = nEp[0];
        double h = 0.75 * (double)(nE - 1);
        long long i0 = (long long)h;
        float frac = (float)(h - (double)i0);
        unsigned int r0 = (unsigned int)i0, r1 = (unsigned int)(i0 + 1);
        unsigned int cum = (tid == 0) ? 0u : psum[tid - 1];
#pragma unroll
        for (int b = 0; b < 32; b++) {
            unsigned int cn = cnt[b];
            unsigned int lo = cum;
            cum += cn;
            if (cn) {
                float v = ((float)(tid * 32 + b) + 0.5f) * (2.0f / (float)NBINS);
                if (lo <= r0 && r0 < cum) vv[0] = v;
                if (lo <= r1 && r1 < cum) vv[1] = v;
            }
        }
        __syncthreads();
        if (tid == 0) {
            float gd = vv[0] + frac * (vv[1] - vv[0]);
            gd = fmaxf(gd, EPSf);
            float alpha = 1.0f / (1.0f + expf(-ralpha[0]));
            float g0 = expf(lg0[0]);
            float r = 1.0f / (1.0f + expf(-rdec[0]));
            float gp = g0;
            for (int q = 0; q < kiter; q++) gp *= r;
            sh_scal = alpha * (gp / SCAD_Af) + (1.0f - alpha) * (gd / SCAD_Af);
        }
        __syncthreads();
    }
    // ---- propagation phase: wave per row, lane = channel ----
    float lamc = sh_scal;
    const float lam = (float)(1.0 / 0.9 - 1.0);
    int i = gid >> 6, c = gid & 63;
    int deg = rowcnt[i];
    float acc = 0.0f, wsum = 0.0f;
    for (int base = 0; base < deg; base += 64) {
        int m = deg - base; if (m > 64) m = 64;
        int   jl = (c < m) ? colIdx[i * MAXD + base + c] : 0;
        float yl = (c < m) ? y_e[i * MAXD + base + c] : 9.0f;
        float il = (c < m) ? isD[jl] : 0.0f;
        int tt = 0;
        for (; tt + 4 <= m; tt += 4) {
            int j0 = __shfl(jl, tt, 64),     j1 = __shfl(jl, tt + 1, 64);
            int j2 = __shfl(jl, tt + 2, 64), j3 = __shfl(jl, tt + 3, 64);
            float f0 = Fc[(size_t)j0 * 64 + c], f1 = Fc[(size_t)j1 * 64 + c];
            float f2 = Fc[(size_t)j2 * 64 + c], f3 = Fc[(size_t)j3 * 64 + c];
            float s0 = scad_w(__shfl(yl, tt, 64),     lamc);
            float s1 = scad_w(__shfl(yl, tt + 1, 64), lamc);
            float s2 = scad_w(__shfl(yl, tt + 2, 64), lamc);
            float s3 = scad_w(__shfl(yl, tt + 3, 64), lamc);
            wsum += s0 + s1 + s2 + s3;
            acc += s0 * __shfl(il, tt, 64) * f0 + s1 * __shfl(il, tt + 1, 64) * f1
                 + s2 * __shfl(il, tt + 2, 64) * f2 + s3 * __shfl(il, tt + 3, 64) * f3;
        }
        for (; tt < m; tt++) {
            int   j = __shfl(jl, tt, 64);
            float y = __shfl(yl, tt, 64);
            float wq = scad_w(y, lamc);
            wsum += wq;
            acc += wq * __shfl(il, tt, 64) * Fc[(size_t)j * 64 + c];
        }
    }
    float Q = wsum / D[i] + lam;
    float fo = (isD[i] * acc + lam * F0[(size_t)i * 64 + c]) / Q;
    Fout[(size_t)i * 64 + c] = fo;
    // fused row-local normalize for the next iteration's edge phase
    float fn = fo * isD[i];
    float s2n = fn * fn;
    for (int off = 32; off; off >>= 1) s2n += __shfl_xor(s2n, off, 64);
    FuNext[(size_t)i * 64 + c] = fn / fmaxf(sqrtf(s2n), EPSf);
}

// ---------------------------------------------------------------------------
extern "C" void kernel_launch(void* const* d_in, const int* in_sizes, int n_in,
                              void* d_out, int out_size, void* d_ws, size_t ws_size,
                              hipStream_t stream) {
    const float* A      = (const float*)d_in[0];
    const float* X      = (const float*)d_in[1];
    const float* W1     = (const float*)d_in[2];
    const float* b1     = (const float*)d_in[3];
    const float* W2     = (const float*)d_in[4];
    const float* b2     = (const float*)d_in[5];
    const float* lg0    = (const float*)d_in[6];
    const float* rdec   = (const float*)d_in[7];
    const float* ralpha = (const float*)d_in[8];
    float* outp = (float*)d_out;

    char* w = (char*)d_ws;
    size_t off = 0;
    auto carve = [&](size_t bytes) -> char* {
        char* p = w + off;
        off += (bytes + 255) & ~(size_t)255;
        return p;
    };
    int*      colIdx = (int*)carve((size_t)N_NODES * MAXD * 4);       // 4 MB padded CSR
    float*    y_e    = (float*)carve((size_t)N_NODES * MAXD * 4);     // 4 MB padded
    float*    part   = (float*)carve((size_t)KSPLIT * N_NODES * H_DIM * 4); // 16 MB
    int*      rowcnt = (int*)carve(N_NODES * 4);
    float*    D      = (float*)carve(N_NODES * 4);
    float*    isD    = (float*)carve(N_NODES * 4);
    float*    Fu     = (float*)carve((size_t)N_NODES * 64 * 4);
    float*    F0     = (float*)carve((size_t)N_NODES * 64 * 4);
    float*    FcA    = (float*)carve((size_t)N_NODES * 64 * 4);
    float*    FcB    = (float*)carve((size_t)N_NODES * 64 * 4);
    unsigned* hist01 = (unsigned*)carve(2 * NBINS * 4);               // double buffer
    int*      nE     = (int*)carve(256);

    // 1: CSR build + gemm1 partials + hist zero (independent work, one launch)
    k_init<<<dim3(2048), dim3(256), 0, stream>>>(A, X, W1, part, colIdx, rowcnt, D, isD, hist01);
    // 2: F0 = relu(X@W1+b1)@W2+b2 (registers-only H1), Fu0, nE
    k_mlp2<<<dim3(1024), dim3(256), 0, stream>>>(part, b1, W2, b2, rowcnt, isD, F0, Fu, nE);

    const float* fin = F0;
    float* fouts[4] = {FcA, FcB, FcA, outp};
    for (int k = 0; k < 4; k++) {
        unsigned* histK    = hist01 + (k & 1) * NBINS;
        unsigned* histNext = hist01 + ((k + 1) & 1) * NBINS;
        k_edgehist<<<dim3(1024), dim3(256), 0, stream>>>(Fu, rowcnt, colIdx, y_e, histK);
        k_propq<<<dim3(1024), dim3(256), 0, stream>>>(histK, histNext, nE, rowcnt, colIdx,
                                                      y_e, fin, F0, D, isD, lg0, rdec,
                                                      ralpha, k, fouts[k], Fu);
        fin = fouts[k];
    }
}

// Round 9
// 342.848 us; speedup vs baseline: 1.1384x; 1.0753x over previous
//
#include <hip/hip_runtime.h>
#include <math.h>

#define N_NODES 4096
#define IN_DIM  512
#define H_DIM   256
#define OUT_DIM 64
#define SCAD_Af 3.7f
#define EPSf    1e-8f
#define NBINS   8192      // 32 KB LDS hist; bin width 2.44e-4 (quantile err << tol)
#define MAXD    256       // padded CSR stride (max degree ~105 stochastically)
#define KSPLIT  4

__device__ __forceinline__ float scad_w(float y, float lamc) {
    if (y <= lamc) return 1.0f;
    if (y <= SCAD_Af * lamc)
        return (SCAD_Af * lamc - y) / ((SCAD_Af - 1.0f) * fmaxf(y, EPSf));
    return 0.0f;
}

// ---------------------------------------------------------------------------
// k_init, grid 2048x256:
//   blocks [0,1024):     gemm1 K-split partials (4 x 64 x 4 tiles linearized)
//   blocks [1024,2048):  degfill (4 rows/block, wave-per-row, float4 A scan,
//                        padded CSR) + zero both histogram buffers
__global__ __launch_bounds__(256)
void k_init(const float* __restrict__ A, const float* __restrict__ X,
            const float* __restrict__ W1, float* __restrict__ part,
            int* __restrict__ colIdx, int* __restrict__ rowcnt,
            float* __restrict__ D, float* __restrict__ isD,
            unsigned int* __restrict__ hist01) {
    __shared__ float As[16][68];
    __shared__ float Bs[16][64];
    __shared__ int cnt4[4];
    int tid = threadIdx.x;
    if (blockIdx.x < 1024) {
        int blk = blockIdx.x;
        int bx = blk & 3, by = (blk >> 2) & 63, bz = blk >> 8;
        int tx = tid & 15, ty = tid >> 4;
        int bm = by * 64, bn = bx * 64;
        int kbeg = bz * (IN_DIM / KSPLIT);
        float acc[4][4] = {};
        for (int k0 = kbeg; k0 < kbeg + IN_DIM / KSPLIT; k0 += 16) {
            {
                int r = tid >> 2, kv = tid & 3;
                float4 v = *(const float4*)(X + (size_t)(bm + r) * IN_DIM + k0 + kv * 4);
                As[kv * 4 + 0][r] = v.x;
                As[kv * 4 + 1][r] = v.y;
                As[kv * 4 + 2][r] = v.z;
                As[kv * 4 + 3][r] = v.w;
            }
            {
                int kk = tid >> 4, nv = tid & 15;
                *(float4*)&Bs[kk][nv * 4] =
                    *(const float4*)(W1 + (size_t)(k0 + kk) * H_DIM + bn + nv * 4);
            }
            __syncthreads();
#pragma unroll
            for (int kk = 0; kk < 16; kk++) {
                float a[4], b[4];
#pragma unroll
                for (int u = 0; u < 4; u++) { a[u] = As[kk][ty * 4 + u]; b[u] = Bs[kk][tx * 4 + u]; }
#pragma unroll
                for (int u = 0; u < 4; u++)
#pragma unroll
                    for (int v = 0; v < 4; v++) acc[u][v] += a[u] * b[v];
            }
            __syncthreads();
        }
        float* Cm = part + (size_t)bz * N_NODES * H_DIM;
#pragma unroll
        for (int u = 0; u < 4; u++) {
            int m = bm + ty * 4 + u;
#pragma unroll
            for (int v = 0; v < 4; v++)
                Cm[(size_t)m * H_DIM + bn + tx * 4 + v] = acc[u][v];
        }
    } else {
        int bb = blockIdx.x - 1024;
        int gid2 = bb * 256 + tid;
        if (gid2 < 2 * NBINS) hist01[gid2] = 0u;   // zero both hist buffers
        int w = tid >> 6, lane = tid & 63;
        int i = bb * 4 + w;
        if (lane == 0) cnt4[w] = 0;
        __syncthreads();
        // float4 scan of row i: 16 B/lane, 1 KB/wave/instr, 16 iterations.
        const float4* row4 = (const float4*)(A + (size_t)i * N_NODES);
        int* ci = colIdx + i * MAXD;
        for (int v = lane; v < N_NODES / 4; v += 64) {
            float4 x = row4[v];
            int j0 = v * 4;
            if (x.x != 0.0f) { int p = atomicAdd(&cnt4[w], 1); ci[p] = j0; }
            if (x.y != 0.0f) { int p = atomicAdd(&cnt4[w], 1); ci[p] = j0 + 1; }
            if (x.z != 0.0f) { int p = atomicAdd(&cnt4[w], 1); ci[p] = j0 + 2; }
            if (x.w != 0.0f) { int p = atomicAdd(&cnt4[w], 1); ci[p] = j0 + 3; }
        }
        __syncthreads();
        if (lane == 0) {
            int t = cnt4[w];
            rowcnt[i] = t;
            float d = (float)t + 1.0f;   // add_loops
            D[i] = d;
            isD[i] = 1.0f / sqrtf(d);
        }
    }
}

// ---------------------------------------------------------------------------
// k_mlp2, grid 1024x256, wave per row.
// Stage: lane l builds H1[i, l+64q] with coalesced independent loads from the
// K-split partials, parks the row in LDS. Dot: lane c runs 4 unrolled fma
// chains over k with coalesced W2 loads (8 in flight). Also emits Fu0 and nE.
__global__ __launch_bounds__(256)
void k_mlp2(const float* __restrict__ part, const float* __restrict__ b1,
            const float* __restrict__ W2, const float* __restrict__ b2,
            const int* __restrict__ rowcnt, const float* __restrict__ isD,
            float* __restrict__ F0, float* __restrict__ Fu, int* __restrict__ nE) {
    __shared__ float sh_h[4][H_DIM];   // per-wave H1 row (4 KB)
    int tid = threadIdx.x;
    if (blockIdx.x == 0) {
        __shared__ unsigned int ps[256];
        unsigned int s = 0;
        for (int q = tid; q < N_NODES; q += 256) s += (unsigned int)rowcnt[q];
        ps[tid] = s;
        __syncthreads();
        for (int off = 128; off; off >>= 1) {
            if (tid < off) ps[tid] += ps[tid + off];
            __syncthreads();
        }
        if (tid == 0) nE[0] = (int)ps[0];
    }
    int w = tid >> 6, lane = tid & 63;
    int i = blockIdx.x * 4 + w;
    const size_t tot = (size_t)N_NODES * H_DIM;
    const float* p0 = part + (size_t)i * H_DIM;
    // ---- stage: coalesced, 16 independent loads per lane ----
#pragma unroll
    for (int q = 0; q < 4; q++) {
        int k = q * 64 + lane;
        float s = p0[k] + p0[tot + k] + p0[2 * tot + k] + p0[3 * tot + k] + b1[k];
        sh_h[w][k] = fmaxf(s, 0.0f);
    }
    // same wave produces & consumes sh_h[w]; lgkmcnt ordering suffices (wave64)
    // ---- dot: 4 chains, unroll 8 -> 8 coalesced W2 loads in flight ----
    const float* W2c = W2 + lane;
    float a0 = 0, a1 = 0, a2 = 0, a3 = 0;
#pragma unroll 8
    for (int k = 0; k < H_DIM; k += 4) {
        a0 += sh_h[w][k + 0] * W2c[(k + 0) * OUT_DIM];
        a1 += sh_h[w][k + 1] * W2c[(k + 1) * OUT_DIM];
        a2 += sh_h[w][k + 2] * W2c[(k + 2) * OUT_DIM];
        a3 += sh_h[w][k + 3] * W2c[(k + 3) * OUT_DIM];
    }
    float f0 = (a0 + a1) + (a2 + a3) + b2[lane];
    F0[(size_t)i * 64 + lane] = f0;
    // fused row-local normalize
    float fn = f0 * isD[i];
    float s2 = fn * fn;
    for (int off = 32; off; off >>= 1) s2 += __shfl_xor(s2, off, 64);
    Fu[(size_t)i * 64 + lane] = fn / fmaxf(sqrtf(s2), EPSf);
}

// ---------------------------------------------------------------------------
// Edge cosine distances + LDS hist. Wave per row, 16 edges in flight.
__global__ __launch_bounds__(256)
void k_edgehist(const float* __restrict__ Fu, const int* __restrict__ rowcnt,
                const int* __restrict__ colIdx, float* __restrict__ y_e,
                unsigned int* __restrict__ histK) {
    __shared__ unsigned int hl[NBINS];
    for (int b = threadIdx.x; b < NBINS; b += 256) hl[b] = 0u;
    __syncthreads();
    int gid = blockIdx.x * 256 + threadIdx.x;
    int ri = gid >> 6;
    int lane = threadIdx.x & 63;
    int eg = lane >> 2, el = lane & 3;
    int deg = rowcnt[ri];
    const float4* Fu4 = (const float4*)Fu;
    float4 fi0 = Fu4[ri * 16 + el * 4 + 0];
    float4 fi1 = Fu4[ri * 16 + el * 4 + 1];
    float4 fi2 = Fu4[ri * 16 + el * 4 + 2];
    float4 fi3 = Fu4[ri * 16 + el * 4 + 3];
    for (int base = 0; base < deg; base += 16) {
        int e = base + eg;
        bool act = e < deg;
        int j = act ? colIdx[ri * MAXD + e] : ri;
        float4 a0 = Fu4[(size_t)j * 16 + el * 4 + 0];
        float4 a1 = Fu4[(size_t)j * 16 + el * 4 + 1];
        float4 a2 = Fu4[(size_t)j * 16 + el * 4 + 2];
        float4 a3 = Fu4[(size_t)j * 16 + el * 4 + 3];
        float s = fi0.x * a0.x + fi0.y * a0.y + fi0.z * a0.z + fi0.w * a0.w
                + fi1.x * a1.x + fi1.y * a1.y + fi1.z * a1.z + fi1.w * a1.w
                + fi2.x * a2.x + fi2.y * a2.y + fi2.z * a2.z + fi2.w * a2.w
                + fi3.x * a3.x + fi3.y * a3.y + fi3.z * a3.z + fi3.w * a3.w;
        s += __shfl_xor(s, 1, 64);
        s += __shfl_xor(s, 2, 64);
        if (act && el == 0) {
            float y = 1.0f - s;
            y = fminf(fmaxf(y, 0.0f), 2.0f);
            y_e[ri * MAXD + e] = y;
            int bin = (int)(y * (NBINS * 0.5f));
            if (bin > NBINS - 1) bin = NBINS - 1;
            atomicAdd(&hl[bin], 1u);
        }
    }
    __syncthreads();
    for (int b = threadIdx.x; b < NBINS; b += 256) {
        unsigned int v = hl[b];
        if (v) atomicAdd(&histK[b], v);   // sparse device-atomic flush
    }
}

// ---------------------------------------------------------------------------
// Quantile (per-block redundant scan of histK) + propagation + fused norm of
// the produced row + zero histNext (double buffer for next iteration).
__global__ __launch_bounds__(256)
void k_propq(const unsigned int* __restrict__ histK, unsigned int* __restrict__ histNext,
             const int* __restrict__ nEp, const int* __restrict__ rowcnt,
             const int* __restrict__ colIdx, const float* __restrict__ y_e,
             const float* __restrict__ Fc, const float* __restrict__ F0,
             const float* __restrict__ D, const float* __restrict__ isD,
             const float* __restrict__ lg0, const float* __restrict__ rdec,
             const float* __restrict__ ralpha, int kiter,
             float* __restrict__ Fout, float* __restrict__ FuNext) {
    __shared__ unsigned int psum[256];
    __shared__ float vv[2];
    __shared__ float sh_scal;
    int tid = threadIdx.x;
    int gid = blockIdx.x * 256 + tid;
    if (gid < NBINS) histNext[gid] = 0u;   // zero the other buffer for next iter
    {   // ---- quantile phase ----
        unsigned int cnt[32];
        const uint4* h4 = (const uint4*)histK;
        unsigned int s = 0;
#pragma unroll
        for (int q = 0; q < 8; q++) {
            uint4 v = h4[tid * 8 + q];
            cnt[q * 4 + 0] = v.x; cnt[q * 4 + 1] = v.y;
            cnt[q * 4 + 2] = v.z; cnt[q * 4 + 3] = v.w;
            s += v.x + v.y + v.z + v.w;
        }
        psum[tid] = s;
        __syncthreads();
        for (int off = 1; off < 256; off <<= 1) {
            unsigned int x = 0;
            if (tid >= off) x = psum[tid - off];
            __syncthreads();
            psum[tid] += x;
            __syncthreads();
        }
        int nE = nEp[0];
        double h = 0.75 * (double)(nE - 1);
        long long i0 = (long long)h;
        float frac = (float)(h - (double)i0);
        unsigned int r0 = (unsigned int)i0, r1 = (unsigned int)(i0 + 1);
        unsigned int cum = (tid == 0) ? 0u : psum[tid - 1];
#pragma unroll
        for (int b = 0; b < 32; b++) {
            unsigned int cn = cnt[b];
            unsigned int lo = cum;
            cum += cn;
            if (cn) {
                float v = ((float)(tid * 32 + b) + 0.5f) * (2.0f / (float)NBINS);
                if (lo <= r0 && r0 < cum) vv[0] = v;
                if (lo <= r1 && r1 < cum) vv[1] = v;
            }
        }
        __syncthreads();
        if (tid == 0) {
            float gd = vv[0] + frac * (vv[1] - vv[0]);
            gd = fmaxf(gd, EPSf);
            float alpha = 1.0f / (1.0f + expf(-ralpha[0]));
            float g0 = expf(lg0[0]);
            float r = 1.0f / (1.0f + expf(-rdec[0]));
            float gp = g0;
            for (int q = 0; q < kiter; q++) gp *= r;
            sh_scal = alpha * (gp / SCAD_Af) + (1.0f - alpha) * (gd / SCAD_Af);
        }
        __syncthreads();
    }
    // ---- propagation phase: wave per row, lane = channel ----
    float lamc = sh_scal;
    const float lam = (float)(1.0 / 0.9 - 1.0);
    int i = gid >> 6, c = gid & 63;
    int deg = rowcnt[i];
    float acc = 0.0f, wsum = 0.0f;
    for (int base = 0; base < deg; base += 64) {
        int m = deg - base; if (m > 64) m = 64;
        int   jl = (c < m) ? colIdx[i * MAXD + base + c] : 0;
        float yl = (c < m) ? y_e[i * MAXD + base + c] : 9.0f;
        float il = (c < m) ? isD[jl] : 0.0f;
        int tt = 0;
        for (; tt + 4 <= m; tt += 4) {
            int j0 = __shfl(jl, tt, 64),     j1 = __shfl(jl, tt + 1, 64);
            int j2 = __shfl(jl, tt + 2, 64), j3 = __shfl(jl, tt + 3, 64);
            float f0 = Fc[(size_t)j0 * 64 + c], f1 = Fc[(size_t)j1 * 64 + c];
            float f2 = Fc[(size_t)j2 * 64 + c], f3 = Fc[(size_t)j3 * 64 + c];
            float s0 = scad_w(__shfl(yl, tt, 64),     lamc);
            float s1 = scad_w(__shfl(yl, tt + 1, 64), lamc);
            float s2 = scad_w(__shfl(yl, tt + 2, 64), lamc);
            float s3 = scad_w(__shfl(yl, tt + 3, 64), lamc);
            wsum += s0 + s1 + s2 + s3;
            acc += s0 * __shfl(il, tt, 64) * f0 + s1 * __shfl(il, tt + 1, 64) * f1
                 + s2 * __shfl(il, tt + 2, 64) * f2 + s3 * __shfl(il, tt + 3, 64) * f3;
        }
        for (; tt < m; tt++) {
            int   j = __shfl(jl, tt, 64);
            float y = __shfl(yl, tt, 64);
            float wq = scad_w(y, lamc);
            wsum += wq;
            acc += wq * __shfl(il, tt, 64) * Fc[(size_t)j * 64 + c];
        }
    }
    float Q = wsum / D[i] + lam;
    float fo = (isD[i] * acc + lam * F0[(size_t)i * 64 + c]) / Q;
    Fout[(size_t)i * 64 + c] = fo;
    // fused row-local normalize for the next iteration's edge phase
    float fn = fo * isD[i];
    float s2n = fn * fn;
    for (int off = 32; off; off >>= 1) s2n += __shfl_xor(s2n, off, 64);
    FuNext[(size_t)i * 64 + c] = fn / fmaxf(sqrtf(s2n), EPSf);
}

// ---------------------------------------------------------------------------
extern "C" void kernel_launch(void* const* d_in, const int* in_sizes, int n_in,
                              void* d_out, int out_size, void* d_ws, size_t ws_size,
                              hipStream_t stream) {
    const float* A      = (const float*)d_in[0];
    const float* X      = (const float*)d_in[1];
    const float* W1     = (const float*)d_in[2];
    const float* b1     = (const float*)d_in[3];
    const float* W2     = (const float*)d_in[4];
    const float* b2     = (const float*)d_in[5];
    const float* lg0    = (const float*)d_in[6];
    const float* rdec   = (const float*)d_in[7];
    const float* ralpha = (const float*)d_in[8];
    float* outp = (float*)d_out;

    char* w = (char*)d_ws;
    size_t off = 0;
    auto carve = [&](size_t bytes) -> char* {
        char* p = w + off;
        off += (bytes + 255) & ~(size_t)255;
        return p;
    };
    int*      colIdx = (int*)carve((size_t)N_NODES * MAXD * 4);       // 4 MB padded CSR
    float*    y_e    = (float*)carve((size_t)N_NODES * MAXD * 4);     // 4 MB padded
    float*    part   = (float*)carve((size_t)KSPLIT * N_NODES * H_DIM * 4); // 16 MB
    int*      rowcnt = (int*)carve(N_NODES * 4);
    float*    D      = (float*)carve(N_NODES * 4);
    float*    isD    = (float*)carve(N_NODES * 4);
    float*    Fu     = (float*)carve((size_t)N_NODES * 64 * 4);
    float*    F0     = (float*)carve((size_t)N_NODES * 64 * 4);
    float*    FcA    = (float*)carve((size_t)N_NODES * 64 * 4);
    float*    FcB    = (float*)carve((size_t)N_NODES * 64 * 4);
    unsigned* hist01 = (unsigned*)carve(2 * NBINS * 4);               // double buffer
    int*      nE     = (int*)carve(256);

    // 1: CSR build + gemm1 partials + hist zero (independent work, one launch)
    k_init<<<dim3(2048), dim3(256), 0, stream>>>(A, X, W1, part, colIdx, rowcnt, D, isD, hist01);
    // 2: F0 = relu(X@W1+b1)@W2+b2 (LDS-staged H1 row), Fu0, nE
    k_mlp2<<<dim3(1024), dim3(256), 0, stream>>>(part, b1, W2, b2, rowcnt, isD, F0, Fu, nE);

    const float* fin = F0;
    float* fouts[4] = {FcA, FcB, FcA, outp};
    for (int k = 0; k < 4; k++) {
        unsigned* histK    = hist01 + (k & 1) * NBINS;
        unsigned* histNext = hist01 + ((k + 1) & 1) * NBINS;
        k_edgehist<<<dim3(1024), dim3(256), 0, stream>>>(Fu, rowcnt, colIdx, y_e, histK);
        k_propq<<<dim3(1024), dim3(256), 0, stream>>>(histK, histNext, nE, rowcnt, colIdx,
                                                      y_e, fin, F0, D, isD, lg0, rdec,
                                                      ralpha, k, fouts[k], Fu);
        fin = fouts[k];
    }
}

// Round 10
// 315.001 us; speedup vs baseline: 1.2391x; 1.0884x over previous
//
#include <hip/hip_runtime.h>
#include <hip/hip_cooperative_groups.h>
#include <math.h>

namespace cg = cooperative_groups;

#define N_NODES 4096
#define IN_DIM  512
#define H_DIM   256
#define OUT_DIM 64
#define SCAD_Af 3.7f
#define EPSf    1e-8f
#define NBINS   2048      // 8 KB LDS hist; bin width 9.8e-4 -> dlam ~6.6e-5 << tol
#define MAXD    256       // padded CSR stride (max degree ~105 stochastically)
#define KSPLIT  4

__device__ __forceinline__ float scad_w(float y, float lamc) {
    if (y <= lamc) return 1.0f;
    if (y <= SCAD_Af * lamc)
        return (SCAD_Af * lamc - y) / ((SCAD_Af - 1.0f) * fmaxf(y, EPSf));
    return 0.0f;
}

// ===========================================================================
// Cooperative mega-kernel: 1024 blocks x 256 threads.
// Phase 0: degfill (4 rows/block) + gemm1 K-split tile + hist zero
// Phase 1: nE + MLP (H1 row staged in LDS) + F0 + Fu0
// 4x: edge+LDS-hist -> sync -> quantile scan + prop + norm -> sync
// ===========================================================================
__global__ __launch_bounds__(256, 4)
void k_mega(const float* __restrict__ A,  const float* __restrict__ X,
            const float* __restrict__ W1, const float* __restrict__ b1,
            const float* __restrict__ W2, const float* __restrict__ b2,
            const float* __restrict__ lg0, const float* __restrict__ rdec,
            const float* __restrict__ ralpha,
            int* __restrict__ colIdx, int* __restrict__ rowcnt,
            float* __restrict__ D, float* __restrict__ isD,
            float* __restrict__ Fu, float* __restrict__ part,
            float* __restrict__ F0, float* __restrict__ FcA,
            float* __restrict__ FcB, float* __restrict__ outp,
            unsigned int* __restrict__ hist01, float* __restrict__ y_e) {
    cg::grid_group grid = cg::this_grid();
    const int tid = threadIdx.x;
    const int blk = blockIdx.x;
    const int gid = blk * 256 + tid;
    const int w = tid >> 6, lane = tid & 63;

    __shared__ union {
        struct { float As[16][68]; float Bs[16][64]; } g;   // 8.45 KB (gemm1)
        unsigned int hl[NBINS];                              // 8 KB (edge phase)
        unsigned int psum[256];                              // 1 KB (quant/nE)
        float sh_h[4][H_DIM];                                // 4 KB (mlp phase)
    } sm;
    __shared__ float vv[2];
    __shared__ float sh_scal;
    __shared__ int   sh_nE;
    __shared__ int   cnt4[4];

    // ---- Phase 0a: degfill, 4 rows/block, float4 A scan ----
    {
        int i = blk * 4 + w;
        if (lane == 0) cnt4[w] = 0;
        __syncthreads();
        const float4* row4 = (const float4*)(A + (size_t)i * N_NODES);
        int* ci = colIdx + i * MAXD;
        for (int v = lane; v < N_NODES / 4; v += 64) {
            float4 x = row4[v];
            int j0 = v * 4;
            if (x.x != 0.0f) { int p = atomicAdd(&cnt4[w], 1); ci[p] = j0; }
            if (x.y != 0.0f) { int p = atomicAdd(&cnt4[w], 1); ci[p] = j0 + 1; }
            if (x.z != 0.0f) { int p = atomicAdd(&cnt4[w], 1); ci[p] = j0 + 2; }
            if (x.w != 0.0f) { int p = atomicAdd(&cnt4[w], 1); ci[p] = j0 + 3; }
        }
        __syncthreads();
        if (lane == 0) {
            int t = cnt4[w];
            rowcnt[i] = t;
            float d = (float)t + 1.0f;   // add_loops
            D[i] = d;
            isD[i] = 1.0f / sqrtf(d);
        }
        if (gid < 2 * NBINS) hist01[gid] = 0u;   // zero both hist buffers
        __syncthreads();
    }
    // ---- Phase 0b: gemm1 K-split tile (blk -> 4 x 64 x 4 linearized) ----
    {
        int bx = blk & 3, by = (blk >> 2) & 63, bz = blk >> 8;
        int tx = tid & 15, ty = tid >> 4;
        int bm = by * 64, bn = bx * 64;
        int kbeg = bz * (IN_DIM / KSPLIT);
        float acc[4][4] = {};
        for (int k0 = kbeg; k0 < kbeg + IN_DIM / KSPLIT; k0 += 16) {
            {
                int r = tid >> 2, kv = tid & 3;
                float4 v = *(const float4*)(X + (size_t)(bm + r) * IN_DIM + k0 + kv * 4);
                sm.g.As[kv * 4 + 0][r] = v.x;
                sm.g.As[kv * 4 + 1][r] = v.y;
                sm.g.As[kv * 4 + 2][r] = v.z;
                sm.g.As[kv * 4 + 3][r] = v.w;
            }
            {
                int kk = tid >> 4, nv = tid & 15;
                *(float4*)&sm.g.Bs[kk][nv * 4] =
                    *(const float4*)(W1 + (size_t)(k0 + kk) * H_DIM + bn + nv * 4);
            }
            __syncthreads();
#pragma unroll
            for (int kk = 0; kk < 16; kk++) {
                float a[4], b[4];
#pragma unroll
                for (int u = 0; u < 4; u++) { a[u] = sm.g.As[kk][ty * 4 + u]; b[u] = sm.g.Bs[kk][tx * 4 + u]; }
#pragma unroll
                for (int u = 0; u < 4; u++)
#pragma unroll
                    for (int v = 0; v < 4; v++) acc[u][v] += a[u] * b[v];
            }
            __syncthreads();
        }
        float* Cm = part + (size_t)bz * N_NODES * H_DIM;
#pragma unroll
        for (int u = 0; u < 4; u++) {
            int m = bm + ty * 4 + u;
#pragma unroll
            for (int v = 0; v < 4; v++)
                Cm[(size_t)m * H_DIM + bn + tx * 4 + v] = acc[u][v];
        }
    }
    grid.sync();

    // ---- Phase 1: nE + MLP (LDS-staged H1 row) + F0 + Fu0 ----
    {
        unsigned int s = 0;
        for (int q = tid; q < N_NODES; q += 256) s += (unsigned int)rowcnt[q];
        sm.psum[tid] = s;
        __syncthreads();
        for (int off = 128; off; off >>= 1) {
            if (tid < off) sm.psum[tid] += sm.psum[tid + off];
            __syncthreads();
        }
        if (tid == 0) sh_nE = (int)sm.psum[0];
        __syncthreads();

        int i = blk * 4 + w;
        const size_t tot = (size_t)N_NODES * H_DIM;
        const float* p0 = part + (size_t)i * H_DIM;
#pragma unroll
        for (int q = 0; q < 4; q++) {
            int k = q * 64 + lane;
            float s2 = p0[k] + p0[tot + k] + p0[2 * tot + k] + p0[3 * tot + k] + b1[k];
            sm.sh_h[w][k] = fmaxf(s2, 0.0f);
        }
        const float* W2c = W2 + lane;
        float a0 = 0, a1 = 0, a2 = 0, a3 = 0;
#pragma unroll 8
        for (int k = 0; k < H_DIM; k += 4) {
            a0 += sm.sh_h[w][k + 0] * W2c[(k + 0) * OUT_DIM];
            a1 += sm.sh_h[w][k + 1] * W2c[(k + 1) * OUT_DIM];
            a2 += sm.sh_h[w][k + 2] * W2c[(k + 2) * OUT_DIM];
            a3 += sm.sh_h[w][k + 3] * W2c[(k + 3) * OUT_DIM];
        }
        float f0 = (a0 + a1) + (a2 + a3) + b2[lane];
        F0[(size_t)i * 64 + lane] = f0;
        float fn = f0 * isD[i];
        float s2 = fn * fn;
        for (int off = 32; off; off >>= 1) s2 += __shfl_xor(s2, off, 64);
        Fu[(size_t)i * 64 + lane] = fn / fmaxf(sqrtf(s2), EPSf);
    }
    grid.sync();

    // ---- Propagation loop ----
    const float lam = (float)(1.0 / 0.9 - 1.0);
    const int eg = lane >> 2, el = lane & 3;
    const int i = gid >> 6, c = gid & 63;
    const float* fin = F0;
    for (int k = 0; k < 4; k++) {
        float* fout = (k == 0) ? FcA : (k == 1) ? FcB : (k == 2) ? FcA : outp;
        unsigned int* histK    = hist01 + (k & 1) * NBINS;
        unsigned int* histNext = hist01 + ((k + 1) & 1) * NBINS;

        // -- edge phase: LDS hist + y_e (16 edges in flight per wave) --
        for (int b = tid; b < NBINS; b += 256) sm.hl[b] = 0u;
        __syncthreads();
        {
            int ri = blk * 4 + w;
            int deg = rowcnt[ri];
            const float4* Fu4 = (const float4*)Fu;
            float4 fi0 = Fu4[ri * 16 + el * 4 + 0];
            float4 fi1 = Fu4[ri * 16 + el * 4 + 1];
            float4 fi2 = Fu4[ri * 16 + el * 4 + 2];
            float4 fi3 = Fu4[ri * 16 + el * 4 + 3];
            for (int base = 0; base < deg; base += 16) {
                int e = base + eg;
                bool act = e < deg;
                int j = act ? colIdx[ri * MAXD + e] : ri;
                float4 a0 = Fu4[(size_t)j * 16 + el * 4 + 0];
                float4 a1 = Fu4[(size_t)j * 16 + el * 4 + 1];
                float4 a2 = Fu4[(size_t)j * 16 + el * 4 + 2];
                float4 a3 = Fu4[(size_t)j * 16 + el * 4 + 3];
                float s = fi0.x * a0.x + fi0.y * a0.y + fi0.z * a0.z + fi0.w * a0.w
                        + fi1.x * a1.x + fi1.y * a1.y + fi1.z * a1.z + fi1.w * a1.w
                        + fi2.x * a2.x + fi2.y * a2.y + fi2.z * a2.z + fi2.w * a2.w
                        + fi3.x * a3.x + fi3.y * a3.y + fi3.z * a3.z + fi3.w * a3.w;
                s += __shfl_xor(s, 1, 64);
                s += __shfl_xor(s, 2, 64);
                if (act && el == 0) {
                    float y = 1.0f - s;
                    y = fminf(fmaxf(y, 0.0f), 2.0f);
                    y_e[ri * MAXD + e] = y;
                    int bin = (int)(y * (NBINS * 0.5f));
                    if (bin > NBINS - 1) bin = NBINS - 1;
                    atomicAdd(&sm.hl[bin], 1u);
                }
            }
        }
        __syncthreads();
        for (int b = tid; b < NBINS; b += 256) {
            unsigned int v = sm.hl[b];
            if (v) atomicAdd(&histK[b], v);
        }
        if (gid < NBINS) histNext[gid] = 0u;   // prep other buffer for next iter
        grid.sync();

        // -- quantile phase: per-block redundant scan of global histK --
        {
            unsigned int cnt[8];
            const uint4* h4 = (const uint4*)histK;
            unsigned int s = 0;
#pragma unroll
            for (int q = 0; q < 2; q++) {
                uint4 v = h4[tid * 2 + q];
                cnt[q * 4 + 0] = v.x; cnt[q * 4 + 1] = v.y;
                cnt[q * 4 + 2] = v.z; cnt[q * 4 + 3] = v.w;
                s += v.x + v.y + v.z + v.w;
            }
            sm.psum[tid] = s;
            __syncthreads();
            for (int off = 1; off < 256; off <<= 1) {
                unsigned int x = 0;
                if (tid >= off) x = sm.psum[tid - off];
                __syncthreads();
                sm.psum[tid] += x;
                __syncthreads();
            }
            int nE = sh_nE;
            double h = 0.75 * (double)(nE - 1);
            long long i0 = (long long)h;
            float frac = (float)(h - (double)i0);
            unsigned int r0 = (unsigned int)i0, r1 = (unsigned int)(i0 + 1);
            unsigned int cum = (tid == 0) ? 0u : sm.psum[tid - 1];
#pragma unroll
            for (int b = 0; b < 8; b++) {
                unsigned int cn = cnt[b];
                unsigned int lo = cum;
                cum += cn;
                if (cn) {
                    float v = ((float)(tid * 8 + b) + 0.5f) * (2.0f / (float)NBINS);
                    if (lo <= r0 && r0 < cum) vv[0] = v;
                    if (lo <= r1 && r1 < cum) vv[1] = v;
                }
            }
            __syncthreads();
            if (tid == 0) {
                float gd = vv[0] + frac * (vv[1] - vv[0]);
                gd = fmaxf(gd, EPSf);
                float alpha = 1.0f / (1.0f + expf(-ralpha[0]));
                float g0 = expf(lg0[0]);
                float r = 1.0f / (1.0f + expf(-rdec[0]));
                float gp = g0;
                for (int q = 0; q < k; q++) gp *= r;
                sh_scal = alpha * (gp / SCAD_Af) + (1.0f - alpha) * (gd / SCAD_Af);
            }
            __syncthreads();
        }
        // -- prop phase: wave per row, lane = channel --
        {
            float lamc = sh_scal;
            int deg = rowcnt[i];
            float acc = 0.0f, wsum = 0.0f;
            for (int base = 0; base < deg; base += 64) {
                int m = deg - base; if (m > 64) m = 64;
                int   jl = (c < m) ? colIdx[i * MAXD + base + c] : 0;
                float yl = (c < m) ? y_e[i * MAXD + base + c] : 9.0f;
                float il = (c < m) ? isD[jl] : 0.0f;
                int tt = 0;
                for (; tt + 4 <= m; tt += 4) {
                    int j0 = __shfl(jl, tt, 64),     j1 = __shfl(jl, tt + 1, 64);
                    int j2 = __shfl(jl, tt + 2, 64), j3 = __shfl(jl, tt + 3, 64);
                    float f0 = fin[(size_t)j0 * 64 + c], f1 = fin[(size_t)j1 * 64 + c];
                    float f2 = fin[(size_t)j2 * 64 + c], f3 = fin[(size_t)j3 * 64 + c];
                    float s0 = scad_w(__shfl(yl, tt, 64),     lamc);
                    float s1 = scad_w(__shfl(yl, tt + 1, 64), lamc);
                    float s2 = scad_w(__shfl(yl, tt + 2, 64), lamc);
                    float s3 = scad_w(__shfl(yl, tt + 3, 64), lamc);
                    wsum += s0 + s1 + s2 + s3;
                    acc += s0 * __shfl(il, tt, 64) * f0 + s1 * __shfl(il, tt + 1, 64) * f1
                         + s2 * __shfl(il, tt + 2, 64) * f2 + s3 * __shfl(il, tt + 3, 64) * f3;
                }
                for (; tt < m; tt++) {
                    int   j = __shfl(jl, tt, 64);
                    float y = __shfl(yl, tt, 64);
                    float wq = scad_w(y, lamc);
                    wsum += wq;
                    acc += wq * __shfl(il, tt, 64) * fin[(size_t)j * 64 + c];
                }
            }
            float Q = wsum / D[i] + lam;
            float fo = (isD[i] * acc + lam * F0[(size_t)i * 64 + c]) / Q;
            fout[(size_t)i * 64 + c] = fo;
            float fn = fo * isD[i];
            float s2n = fn * fn;
            for (int off = 32; off; off >>= 1) s2n += __shfl_xor(s2n, off, 64);
            Fu[(size_t)i * 64 + c] = fn / fmaxf(sqrtf(s2n), EPSf);
        }
        grid.sync();
        fin = fout;
    }
}

// ===========================================================================
// Fallback path (round-9 structure, NBINS 2048) — used if cooperative launch
// is unavailable / rejected by the occupancy gate.
// ===========================================================================
__global__ __launch_bounds__(256)
void k_init(const float* __restrict__ A, const float* __restrict__ X,
            const float* __restrict__ W1, float* __restrict__ part,
            int* __restrict__ colIdx, int* __restrict__ rowcnt,
            float* __restrict__ D, float* __restrict__ isD,
            unsigned int* __restrict__ hist01) {
    __shared__ float As[16][68];
    __shared__ float Bs[16][64];
    __shared__ int cnt4[4];
    int tid = threadIdx.x;
    if (blockIdx.x < 1024) {
        int blk = blockIdx.x;
        int bx = blk & 3, by = (blk >> 2) & 63, bz = blk >> 8;
        int tx = tid & 15, ty = tid >> 4;
        int bm = by * 64, bn = bx * 64;
        int kbeg = bz * (IN_DIM / KSPLIT);
        float acc[4][4] = {};
        for (int k0 = kbeg; k0 < kbeg + IN_DIM / KSPLIT; k0 += 16) {
            {
                int r = tid >> 2, kv = tid & 3;
                float4 v = *(const float4*)(X + (size_t)(bm + r) * IN_DIM + k0 + kv * 4);
                As[kv * 4 + 0][r] = v.x;
                As[kv * 4 + 1][r] = v.y;
                As[kv * 4 + 2][r] = v.z;
                As[kv * 4 + 3][r] = v.w;
            }
            {
                int kk = tid >> 4, nv = tid & 15;
                *(float4*)&Bs[kk][nv * 4] =
                    *(const float4*)(W1 + (size_t)(k0 + kk) * H_DIM + bn + nv * 4);
            }
            __syncthreads();
#pragma unroll
            for (int kk = 0; kk < 16; kk++) {
                float a[4], b[4];
#pragma unroll
                for (int u = 0; u < 4; u++) { a[u] = As[kk][ty * 4 + u]; b[u] = Bs[kk][tx * 4 + u]; }
#pragma unroll
                for (int u = 0; u < 4; u++)
#pragma unroll
                    for (int v = 0; v < 4; v++) acc[u][v] += a[u] * b[v];
            }
            __syncthreads();
        }
        float* Cm = part + (size_t)bz * N_NODES * H_DIM;
#pragma unroll
        for (int u = 0; u < 4; u++) {
            int m = bm + ty * 4 + u;
#pragma unroll
            for (int v = 0; v < 4; v++)
                Cm[(size_t)m * H_DIM + bn + tx * 4 + v] = acc[u][v];
        }
    } else {
        int bb = blockIdx.x - 1024;
        int gid2 = bb * 256 + tid;
        if (gid2 < 2 * NBINS) hist01[gid2] = 0u;
        int w = tid >> 6, lane = tid & 63;
        int i = bb * 4 + w;
        if (lane == 0) cnt4[w] = 0;
        __syncthreads();
        const float4* row4 = (const float4*)(A + (size_t)i * N_NODES);
        int* ci = colIdx + i * MAXD;
        for (int v = lane; v < N_NODES / 4; v += 64) {
            float4 x = row4[v];
            int j0 = v * 4;
            if (x.x != 0.0f) { int p = atomicAdd(&cnt4[w], 1); ci[p] = j0; }
            if (x.y != 0.0f) { int p = atomicAdd(&cnt4[w], 1); ci[p] = j0 + 1; }
            if (x.z != 0.0f) { int p = atomicAdd(&cnt4[w], 1); ci[p] = j0 + 2; }
            if (x.w != 0.0f) { int p = atomicAdd(&cnt4[w], 1); ci[p] = j0 + 3; }
        }
        __syncthreads();
        if (lane == 0) {
            int t = cnt4[w];
            rowcnt[i] = t;
            float d = (float)t + 1.0f;
            D[i] = d;
            isD[i] = 1.0f / sqrtf(d);
        }
    }
}

__global__ __launch_bounds__(256)
void k_mlp2(const float* __restrict__ part, const float* __restrict__ b1,
            const float* __restrict__ W2, const float* __restrict__ b2,
            const int* __restrict__ rowcnt, const float* __restrict__ isD,
            float* __restrict__ F0, float* __restrict__ Fu, int* __restrict__ nE) {
    __shared__ float sh_h[4][H_DIM];
    int tid = threadIdx.x;
    if (blockIdx.x == 0) {
        __shared__ unsigned int ps[256];
        unsigned int s = 0;
        for (int q = tid; q < N_NODES; q += 256) s += (unsigned int)rowcnt[q];
        ps[tid] = s;
        __syncthreads();
        for (int off = 128; off; off >>= 1) {
            if (tid < off) ps[tid] += ps[tid + off];
            __syncthreads();
        }
        if (tid == 0) nE[0] = (int)ps[0];
    }
    int w = tid >> 6, lane = tid & 63;
    int i = blockIdx.x * 4 + w;
    const size_t tot = (size_t)N_NODES * H_DIM;
    const float* p0 = part + (size_t)i * H_DIM;
#pragma unroll
    for (int q = 0; q < 4; q++) {
        int k = q * 64 + lane;
        float s = p0[k] + p0[tot + k] + p0[2 * tot + k] + p0[3 * tot + k] + b1[k];
        sh_h[w][k] = fmaxf(s, 0.0f);
    }
    const float* W2c = W2 + lane;
    float a0 = 0, a1 = 0, a2 = 0, a3 = 0;
#pragma unroll 8
    for (int k = 0; k < H_DIM; k += 4) {
        a0 += sh_h[w][k + 0] * W2c[(k + 0) * OUT_DIM];
        a1 += sh_h[w][k + 1] * W2c[(k + 1) * OUT_DIM];
        a2 += sh_h[w][k + 2] * W2c[(k + 2) * OUT_DIM];
        a3 += sh_h[w][k + 3] * W2c[(k + 3) * OUT_DIM];
    }
    float f0 = (a0 + a1) + (a2 + a3) + b2[lane];
    F0[(size_t)i * 64 + lane] = f0;
    float fn = f0 * isD[i];
    float s2 = fn * fn;
    for (int off = 32; off; off >>= 1) s2 += __shfl_xor(s2, off, 64);
    Fu[(size_t)i * 64 + lane] = fn / fmaxf(sqrtf(s2), EPSf);
}

__global__ __launch_bounds__(256)
void k_edgehist(const float* __restrict__ Fu, const int* __restrict__ rowcnt,
                const int* __restrict__ colIdx, float* __restrict__ y_e,
                unsigned int* __restrict__ histK) {
    __shared__ unsigned int hl[NBINS];
    for (int b = threadIdx.x; b < NBINS; b += 256) hl[b] = 0u;
    __syncthreads();
    int gid = blockIdx.x * 256 + threadIdx.x;
    int ri = gid >> 6;
    int lane = threadIdx.x & 63;
    int eg = lane >> 2, el = lane & 3;
    int deg = rowcnt[ri];
    const float4* Fu4 = (const float4*)Fu;
    float4 fi0 = Fu4[ri * 16 + el * 4 + 0];
    float4 fi1 = Fu4[ri * 16 + el * 4 + 1];
    float4 fi2 = Fu4[ri * 16 + el * 4 + 2];
    float4 fi3 = Fu4[ri * 16 + el * 4 + 3];
    for (int base = 0; base < deg; base += 16) {
        int e = base + eg;
        bool act = e < deg;
        int j = act ? colIdx[ri * MAXD + e] : ri;
        float4 a0 = Fu4[(size_t)j * 16 + el * 4 + 0];
        float4 a1 = Fu4[(size_t)j * 16 + el * 4 + 1];
        float4 a2 = Fu4[(size_t)j * 16 + el * 4 + 2];
        float4 a3 = Fu4[(size_t)j * 16 + el * 4 + 3];
        float s = fi0.x * a0.x + fi0.y * a0.y + fi0.z * a0.z + fi0.w * a0.w
                + fi1.x * a1.x + fi1.y * a1.y + fi1.z * a1.z + fi1.w * a1.w
                + fi2.x * a2.x + fi2.y * a2.y + fi2.z * a2.z + fi2.w * a2.w
                + fi3.x * a3.x + fi3.y * a3.y + fi3.z * a3.z + fi3.w * a3.w;
        s += __shfl_xor(s, 1, 64);
        s += __shfl_xor(s, 2, 64);
        if (act && el == 0) {
            float y = 1.0f - s;
            y = fminf(fmaxf(y, 0.0f), 2.0f);
            y_e[ri * MAXD + e] = y;
            int bin = (int)(y * (NBINS * 0.5f));
            if (bin > NBINS - 1) bin = NBINS - 1;
            atomicAdd(&hl[bin], 1u);
        }
    }
    __syncthreads();
    for (int b = threadIdx.x; b < NBINS; b += 256) {
        unsigned int v = hl[b];
        if (v) atomicAdd(&histK[b], v);
    }
}

__global__ __launch_bounds__(256)
void k_propq(const unsigned int* __restrict__ histK, unsigned int* __restrict__ histNext,
             const int* __restrict__ nEp, const int* __restrict__ rowcnt,
             const int* __restrict__ colIdx, const float* __restrict__ y_e,
             const float* __restrict__ Fc, const float* __restrict__ F0,
             const float* __restrict__ D, const float* __restrict__ isD,
             const float* __restrict__ lg0, const float* __restrict__ rdec,
             const float* __restrict__ ralpha, int kiter,
             float* __restrict__ Fout, float* __restrict__ FuNext) {
    __shared__ unsigned int psum[256];
    __shared__ float vv[2];
    __shared__ float sh_scal;
    int tid = threadIdx.x;
    int gid = blockIdx.x * 256 + tid;
    if (gid < NBINS) histNext[gid] = 0u;
    {
        unsigned int cnt[8];
        const uint4* h4 = (const uint4*)histK;
        unsigned int s = 0;
#pragma unroll
        for (int q = 0; q < 2; q++) {
            uint4 v = h4[tid * 2 + q];
            cnt[q * 4 + 0] = v.x; cnt[q * 4 + 1] = v.y;
            cnt[q * 4 + 2] = v.z; cnt[q * 4 + 3] = v.w;
            s += v.x + v.y + v.z + v.w;
        }
        psum[tid] = s;
        __syncthreads();
        for (int off = 1; off < 256; off <<= 1) {
            unsigned int x = 0;
            if (tid >= off) x = psum[tid - off];
            __syncthreads();
            psum[tid] += x;
            __syncthreads();
        }
        int nE = nEp[0];
        double h = 0.75 * (double)(nE - 1);
        long long i0 = (long long)h;
        float frac = (float)(h - (double)i0);
        unsigned int r0 = (unsigned int)i0, r1 = (unsigned int)(i0 + 1);
        unsigned int cum = (tid == 0) ? 0u : psum[tid - 1];
#pragma unroll
        for (int b = 0; b < 8; b++) {
            unsigned int cn = cnt[b];
            unsigned int lo = cum;
            cum += cn;
            if (cn) {
                float v = ((float)(tid * 8 + b) + 0.5f) * (2.0f / (float)NBINS);
                if (lo <= r0 && r0 < cum) vv[0] = v;
                if (lo <= r1 && r1 < cum) vv[1] = v;
            }
        }
        __syncthreads();
        if (tid == 0) {
            float gd = vv[0] + frac * (vv[1] - vv[0]);
            gd = fmaxf(gd, EPSf);
            float alpha = 1.0f / (1.0f + expf(-ralpha[0]));
            float g0 = expf(lg0[0]);
            float r = 1.0f / (1.0f + expf(-rdec[0]));
            float gp = g0;
            for (int q = 0; q < kiter; q++) gp *= r;
            sh_scal = alpha * (gp / SCAD_Af) + (1.0f - alpha) * (gd / SCAD_Af);
        }
        __syncthreads();
    }
    float lamc = sh_scal;
    const float lam = (float)(1.0 / 0.9 - 1.0);
    int i = gid >> 6, c = gid & 63;
    int deg = rowcnt[i];
    float acc = 0.0f, wsum = 0.0f;
    for (int base = 0; base < deg; base += 64) {
        int m = deg - base; if (m > 64) m = 64;
        int   jl = (c < m) ? colIdx[i * MAXD + base + c] : 0;
        float yl = (c < m) ? y_e[i * MAXD + base + c] : 9.0f;
        float il = (c < m) ? isD[jl] : 0.0f;
        int tt = 0;
        for (; tt + 4 <= m; tt += 4) {
            int j0 = __shfl(jl, tt, 64),     j1 = __shfl(jl, tt + 1, 64);
            int j2 = __shfl(jl, tt + 2, 64), j3 = __shfl(jl, tt + 3, 64);
            float f0 = Fc[(size_t)j0 * 64 + c], f1 = Fc[(size_t)j1 * 64 + c];
            float f2 = Fc[(size_t)j2 * 64 + c], f3 = Fc[(size_t)j3 * 64 + c];
            float s0 = scad_w(__shfl(yl, tt, 64),     lamc);
            float s1 = scad_w(__shfl(yl, tt + 1, 64), lamc);
            float s2 = scad_w(__shfl(yl, tt + 2, 64), lamc);
            float s3 = scad_w(__shfl(yl, tt + 3, 64), lamc);
            wsum += s0 + s1 + s2 + s3;
            acc += s0 * __shfl(il, tt, 64) * f0 + s1 * __shfl(il, tt + 1, 64) * f1
                 + s2 * __shfl(il, tt + 2, 64) * f2 + s3 * __shfl(il, tt + 3, 64) * f3;
        }
        for (; tt < m; tt++) {
            int   j = __shfl(jl, tt, 64);
            float y = __shfl(yl, tt, 64);
            float wq = scad_w(y, lamc);
            wsum += wq;
            acc += wq * __shfl(il, tt, 64) * Fc[(size_t)j * 64 + c];
        }
    }
    float Q = wsum / D[i] + lam;
    float fo = (isD[i] * acc + lam * F0[(size_t)i * 64 + c]) / Q;
    Fout[(size_t)i * 64 + c] = fo;
    float fn = fo * isD[i];
    float s2n = fn * fn;
    for (int off = 32; off; off >>= 1) s2n += __shfl_xor(s2n, off, 64);
    FuNext[(size_t)i * 64 + c] = fn / fmaxf(sqrtf(s2n), EPSf);
}

// ---------------------------------------------------------------------------
extern "C" void kernel_launch(void* const* d_in, const int* in_sizes, int n_in,
                              void* d_out, int out_size, void* d_ws, size_t ws_size,
                              hipStream_t stream) {
    const float* A      = (const float*)d_in[0];
    const float* X      = (const float*)d_in[1];
    const float* W1     = (const float*)d_in[2];
    const float* b1     = (const float*)d_in[3];
    const float* W2     = (const float*)d_in[4];
    const float* b2     = (const float*)d_in[5];
    const float* lg0    = (const float*)d_in[6];
    const float* rdec   = (const float*)d_in[7];
    const float* ralpha = (const float*)d_in[8];
    float* outp = (float*)d_out;

    char* w = (char*)d_ws;
    size_t off = 0;
    auto carve = [&](size_t bytes) -> char* {
        char* p = w + off;
        off += (bytes + 255) & ~(size_t)255;
        return p;
    };
    int*      colIdx = (int*)carve((size_t)N_NODES * MAXD * 4);
    float*    y_e    = (float*)carve((size_t)N_NODES * MAXD * 4);
    float*    part   = (float*)carve((size_t)KSPLIT * N_NODES * H_DIM * 4);
    int*      rowcnt = (int*)carve(N_NODES * 4);
    float*    D      = (float*)carve(N_NODES * 4);
    float*    isD    = (float*)carve(N_NODES * 4);
    float*    Fu     = (float*)carve((size_t)N_NODES * 64 * 4);
    float*    F0     = (float*)carve((size_t)N_NODES * 64 * 4);
    float*    FcA    = (float*)carve((size_t)N_NODES * 64 * 4);
    float*    FcB    = (float*)carve((size_t)N_NODES * 64 * 4);
    unsigned* hist01 = (unsigned*)carve(2 * NBINS * 4);
    int*      nE     = (int*)carve(256);

    // Deterministic, capture-safe gate for the cooperative path.
    int coopAttr = 0, numCU = 0, maxPerCU = 0;
    (void)hipDeviceGetAttribute(&coopAttr, hipDeviceAttributeCooperativeLaunch, 0);
    (void)hipDeviceGetAttribute(&numCU, hipDeviceAttributeMultiprocessorCount, 0);
    (void)hipOccupancyMaxActiveBlocksPerMultiprocessor(&maxPerCU, k_mega, 256, 0);
    bool useCoop = (coopAttr != 0) && ((long)maxPerCU * (long)numCU >= 1024);

    if (useCoop) {
        void* args[] = {
            (void*)&A, (void*)&X, (void*)&W1, (void*)&b1, (void*)&W2, (void*)&b2,
            (void*)&lg0, (void*)&rdec, (void*)&ralpha,
            (void*)&colIdx, (void*)&rowcnt, (void*)&D, (void*)&isD,
            (void*)&Fu, (void*)&part, (void*)&F0,
            (void*)&FcA, (void*)&FcB, (void*)&outp, (void*)&hist01, (void*)&y_e,
        };
        hipError_t e = hipLaunchCooperativeKernel((void*)k_mega, dim3(1024), dim3(256),
                                                  args, 0, stream);
        if (e == hipSuccess) return;
        (void)hipGetLastError();   // clear sticky error; fall through to fallback
    }

    // Fallback: proven 10-kernel path.
    k_init<<<dim3(2048), dim3(256), 0, stream>>>(A, X, W1, part, colIdx, rowcnt, D, isD, hist01);
    k_mlp2<<<dim3(1024), dim3(256), 0, stream>>>(part, b1, W2, b2, rowcnt, isD, F0, Fu, nE);
    const float* fin = F0;
    float* fouts[4] = {FcA, FcB, FcA, outp};
    for (int k = 0; k < 4; k++) {
        unsigned* histK    = hist01 + (k & 1) * NBINS;
        unsigned* histNext = hist01 + ((k + 1) & 1) * NBINS;
        k_edgehist<<<dim3(1024), dim3(256), 0, stream>>>(Fu, rowcnt, colIdx, y_e, histK);
        k_propq<<<dim3(1024), dim3(256), 0, stream>>>(histK, histNext, nE, rowcnt, colIdx,
                                                      y_e, fin, F0, D, isD, lg0, rdec,
                                                      ralpha, k, fouts[k], Fu);
        fin = fouts[k];
    }
}

// Round 11
// 307.565 us; speedup vs baseline: 1.2690x; 1.0242x over previous
//
#include <hip/hip_runtime.h>
#include <hip/hip_cooperative_groups.h>
#include <math.h>

namespace cg = cooperative_groups;

#define N_NODES 4096
#define IN_DIM  512
#define H_DIM   256
#define OUT_DIM 64
#define SCAD_Af 3.7f
#define EPSf    1e-8f
#define NBINS   2048      // 8 KB LDS hist; bin width 9.8e-4 -> dlam ~6.6e-5 << tol
#define MAXD    256       // padded CSR stride (max degree ~100 stochastically)
#define KSPLIT  4         // fallback path K-split
#define KS_MG   2         // mega-kernel K-split (512 gemm blocks, 2/CU)

__device__ __forceinline__ float scad_w(float y, float lamc) {
    if (y <= lamc) return 1.0f;
    if (y <= SCAD_Af * lamc)
        return (SCAD_Af * lamc - y) / ((SCAD_Af - 1.0f) * fmaxf(y, EPSf));
    return 0.0f;
}

// ===========================================================================
// Cooperative mega-kernel: 1024 blocks x 256 threads (persistent blocks).
// Phase 0 (role-split): blocks [0,512) gemm1 K-split-2 tiles;
//                       blocks [512,1024) degfill 8 rows + hist zero.
// Phase 1: nE + MLP (H1 row in LDS, W2 chunk-staged in LDS) -> F0, Fu0.
// 4x: edge (y in LDS, LDS hist) -> sync -> quantile + prop + norm -> sync.
// ===========================================================================
__global__ __launch_bounds__(256, 4)
void k_mega(const float* __restrict__ A,  const float* __restrict__ X,
            const float* __restrict__ W1, const float* __restrict__ b1,
            const float* __restrict__ W2, const float* __restrict__ b2,
            const float* __restrict__ lg0, const float* __restrict__ rdec,
            const float* __restrict__ ralpha,
            int* __restrict__ colIdx, int* __restrict__ rowcnt,
            float* __restrict__ D, float* __restrict__ isD,
            float* __restrict__ Fu, float* __restrict__ part,
            float* __restrict__ F0, float* __restrict__ FcA,
            float* __restrict__ FcB, float* __restrict__ outp,
            unsigned int* __restrict__ hist01) {
    cg::grid_group grid = cg::this_grid();
    const int tid = threadIdx.x;
    const int blk = blockIdx.x;
    const int gid = blk * 256 + tid;
    const int w = tid >> 6, lane = tid & 63;

    __shared__ union {
        struct { float As[16][68]; float Bs[16][64]; } g;     // 8.45 KB (gemm)
        unsigned int hl[NBINS];                               // 8 KB (edge)
        unsigned int psum[256];                               // 1 KB (quant/nE)
        struct { float h[4][H_DIM]; float w2[64][64]; } m;    // 20 KB (mlp)
    } sm;
    __shared__ float y_loc[4][MAXD];   // per-row y cache, survives grid.sync (4 KB)
    __shared__ float vv[2];
    __shared__ float sh_scal;
    __shared__ int   sh_nE;
    __shared__ int   cnt4[4];

    // ---- Phase 0 (role-split) ----
    if (blk < 512) {
        // gemm1 tile: bz in {0,1}, 256 tiles each (4 x 64)
        int bz = blk >> 8, rem = blk & 255;
        int bx = rem & 3, by = rem >> 2;
        int tx = tid & 15, ty = tid >> 4;
        int bm = by * 64, bn = bx * 64;
        int kbeg = bz * (IN_DIM / KS_MG);
        float acc[4][4] = {};
        for (int k0 = kbeg; k0 < kbeg + IN_DIM / KS_MG; k0 += 16) {
            {
                int r = tid >> 2, kv = tid & 3;
                float4 v = *(const float4*)(X + (size_t)(bm + r) * IN_DIM + k0 + kv * 4);
                sm.g.As[kv * 4 + 0][r] = v.x;
                sm.g.As[kv * 4 + 1][r] = v.y;
                sm.g.As[kv * 4 + 2][r] = v.z;
                sm.g.As[kv * 4 + 3][r] = v.w;
            }
            {
                int kk = tid >> 4, nv = tid & 15;
                *(float4*)&sm.g.Bs[kk][nv * 4] =
                    *(const float4*)(W1 + (size_t)(k0 + kk) * H_DIM + bn + nv * 4);
            }
            __syncthreads();
#pragma unroll
            for (int kk = 0; kk < 16; kk++) {
                float a[4], b[4];
#pragma unroll
                for (int u = 0; u < 4; u++) { a[u] = sm.g.As[kk][ty * 4 + u]; b[u] = sm.g.Bs[kk][tx * 4 + u]; }
#pragma unroll
                for (int u = 0; u < 4; u++)
#pragma unroll
                    for (int v = 0; v < 4; v++) acc[u][v] += a[u] * b[v];
            }
            __syncthreads();
        }
        float* Cm = part + (size_t)bz * N_NODES * H_DIM;
#pragma unroll
        for (int u = 0; u < 4; u++) {
            int m2 = bm + ty * 4 + u;
#pragma unroll
            for (int v = 0; v < 4; v++)
                Cm[(size_t)m2 * H_DIM + bn + tx * 4 + v] = acc[u][v];
        }
    } else {
        int bb = blk - 512;                      // 0..511
        int gid2 = bb * 256 + tid;
        if (gid2 < 2 * NBINS) hist01[gid2] = 0u; // zero both hist buffers
        // degfill: 8 rows/block, wave w does rows bb*8 + w and bb*8 + 4 + w
#pragma unroll
        for (int rr = 0; rr < 2; rr++) {
            int i = bb * 8 + rr * 4 + w;
            if (lane == 0) cnt4[w] = 0;          // wave-private counter (lockstep)
            const float4* row4 = (const float4*)(A + (size_t)i * N_NODES);
            int* ci = colIdx + i * MAXD;
            for (int v = lane; v < N_NODES / 4; v += 64) {
                float4 x = row4[v];
                int j0 = v * 4;
                if (x.x != 0.0f) { int p = atomicAdd(&cnt4[w], 1); ci[p] = j0; }
                if (x.y != 0.0f) { int p = atomicAdd(&cnt4[w], 1); ci[p] = j0 + 1; }
                if (x.z != 0.0f) { int p = atomicAdd(&cnt4[w], 1); ci[p] = j0 + 2; }
                if (x.w != 0.0f) { int p = atomicAdd(&cnt4[w], 1); ci[p] = j0 + 3; }
            }
            if (lane == 0) {
                int t = cnt4[w];
                rowcnt[i] = t;
                float d = (float)t + 1.0f;   // add_loops
                D[i] = d;
                isD[i] = 1.0f / sqrtf(d);
            }
        }
    }
    grid.sync();

    // ---- Phase 1: nE + MLP ----
    {
        unsigned int s = 0;
        for (int q = tid; q < N_NODES; q += 256) s += (unsigned int)rowcnt[q];
        sm.psum[tid] = s;
        __syncthreads();
        for (int off = 128; off; off >>= 1) {
            if (tid < off) sm.psum[tid] += sm.psum[tid + off];
            __syncthreads();
        }
        if (tid == 0) sh_nE = (int)sm.psum[0];
        __syncthreads();

        // H1 row i staged in LDS (wave-private), W2 chunk-staged block-wide.
        int i = blk * 4 + w;
        const size_t tot = (size_t)N_NODES * H_DIM;
        const float* p0 = part + (size_t)i * H_DIM;
#pragma unroll
        for (int q = 0; q < 4; q++) {
            int k = q * 64 + lane;
            float s2 = p0[k] + p0[tot + k] + b1[k];   // KS_MG = 2 partials
            sm.m.h[w][k] = fmaxf(s2, 0.0f);
        }
        float a0 = 0, a1 = 0, a2 = 0, a3 = 0;
        for (int k0 = 0; k0 < H_DIM; k0 += 64) {
            __syncthreads();
            // stage W2[k0..k0+64)[0..64) -> sm.m.w2 (1024 float4s)
            const float4* src = (const float4*)(W2 + (size_t)k0 * OUT_DIM);
#pragma unroll
            for (int q = 0; q < 4; q++)
                ((float4*)sm.m.w2)[q * 256 + tid] = src[q * 256 + tid];
            __syncthreads();
#pragma unroll 16
            for (int kk = 0; kk < 64; kk += 4) {
                a0 += sm.m.h[w][k0 + kk + 0] * sm.m.w2[kk + 0][lane];
                a1 += sm.m.h[w][k0 + kk + 1] * sm.m.w2[kk + 1][lane];
                a2 += sm.m.h[w][k0 + kk + 2] * sm.m.w2[kk + 2][lane];
                a3 += sm.m.h[w][k0 + kk + 3] * sm.m.w2[kk + 3][lane];
            }
        }
        float f0 = (a0 + a1) + (a2 + a3) + b2[lane];
        F0[(size_t)i * 64 + lane] = f0;
        float fn = f0 * isD[i];
        float s2 = fn * fn;
        for (int off = 32; off; off >>= 1) s2 += __shfl_xor(s2, off, 64);
        Fu[(size_t)i * 64 + lane] = fn / fmaxf(sqrtf(s2), EPSf);
    }
    grid.sync();

    // ---- Propagation loop ----
    const float lam = (float)(1.0 / 0.9 - 1.0);
    const int eg = lane >> 2, el = lane & 3;
    const int i = blk * 4 + w, c = lane;
    const float* fin = F0;
    for (int k = 0; k < 4; k++) {
        float* fout = (k == 0) ? FcA : (k == 1) ? FcB : (k == 2) ? FcA : outp;
        unsigned int* histK    = hist01 + (k & 1) * NBINS;
        unsigned int* histNext = hist01 + ((k + 1) & 1) * NBINS;

        // -- edge phase: y into LDS + LDS hist (16 edges in flight per wave) --
        for (int b = tid; b < NBINS; b += 256) sm.hl[b] = 0u;
        __syncthreads();
        {
            int deg = rowcnt[i];
            const float4* Fu4 = (const float4*)Fu;
            float4 fi0 = Fu4[i * 16 + el * 4 + 0];
            float4 fi1 = Fu4[i * 16 + el * 4 + 1];
            float4 fi2 = Fu4[i * 16 + el * 4 + 2];
            float4 fi3 = Fu4[i * 16 + el * 4 + 3];
            for (int base = 0; base < deg; base += 16) {
                int e = base + eg;
                bool act = e < deg;
                int j = act ? colIdx[i * MAXD + e] : i;
                float4 a0 = Fu4[(size_t)j * 16 + el * 4 + 0];
                float4 a1 = Fu4[(size_t)j * 16 + el * 4 + 1];
                float4 a2 = Fu4[(size_t)j * 16 + el * 4 + 2];
                float4 a3 = Fu4[(size_t)j * 16 + el * 4 + 3];
                float s = fi0.x * a0.x + fi0.y * a0.y + fi0.z * a0.z + fi0.w * a0.w
                        + fi1.x * a1.x + fi1.y * a1.y + fi1.z * a1.z + fi1.w * a1.w
                        + fi2.x * a2.x + fi2.y * a2.y + fi2.z * a2.z + fi2.w * a2.w
                        + fi3.x * a3.x + fi3.y * a3.y + fi3.z * a3.z + fi3.w * a3.w;
                s += __shfl_xor(s, 1, 64);
                s += __shfl_xor(s, 2, 64);
                if (act && el == 0) {
                    float y = 1.0f - s;
                    y = fminf(fmaxf(y, 0.0f), 2.0f);
                    y_loc[w][e] = y;                       // stays in LDS
                    int bin = (int)(y * (NBINS * 0.5f));
                    if (bin > NBINS - 1) bin = NBINS - 1;
                    atomicAdd(&sm.hl[bin], 1u);
                }
            }
        }
        __syncthreads();
        for (int b = tid; b < NBINS; b += 256) {
            unsigned int v = sm.hl[b];
            if (v) atomicAdd(&histK[b], v);
        }
        if (tid < 4 && blk * 4 + tid < NBINS) {}           // (no-op placeholder)
        if (gid < NBINS) histNext[gid] = 0u;               // prep next buffer
        grid.sync();

        // -- quantile phase: per-block redundant scan of global histK --
        {
            unsigned int cnt[8];
            const uint4* h4 = (const uint4*)histK;
            unsigned int s = 0;
#pragma unroll
            for (int q = 0; q < 2; q++) {
                uint4 v = h4[tid * 2 + q];
                cnt[q * 4 + 0] = v.x; cnt[q * 4 + 1] = v.y;
                cnt[q * 4 + 2] = v.z; cnt[q * 4 + 3] = v.w;
                s += v.x + v.y + v.z + v.w;
            }
            sm.psum[tid] = s;
            __syncthreads();
            for (int off = 1; off < 256; off <<= 1) {
                unsigned int x = 0;
                if (tid >= off) x = sm.psum[tid - off];
                __syncthreads();
                sm.psum[tid] += x;
                __syncthreads();
            }
            int nE = sh_nE;
            double h = 0.75 * (double)(nE - 1);
            long long i0 = (long long)h;
            float frac = (float)(h - (double)i0);
            unsigned int r0 = (unsigned int)i0, r1 = (unsigned int)(i0 + 1);
            unsigned int cum = (tid == 0) ? 0u : sm.psum[tid - 1];
#pragma unroll
            for (int b = 0; b < 8; b++) {
                unsigned int cn = cnt[b];
                unsigned int lo = cum;
                cum += cn;
                if (cn) {
                    float v = ((float)(tid * 8 + b) + 0.5f) * (2.0f / (float)NBINS);
                    if (lo <= r0 && r0 < cum) vv[0] = v;
                    if (lo <= r1 && r1 < cum) vv[1] = v;
                }
            }
            __syncthreads();
            if (tid == 0) {
                float gd = vv[0] + frac * (vv[1] - vv[0]);
                gd = fmaxf(gd, EPSf);
                float alpha = 1.0f / (1.0f + expf(-ralpha[0]));
                float g0 = expf(lg0[0]);
                float r = 1.0f / (1.0f + expf(-rdec[0]));
                float gp = g0;
                for (int q = 0; q < k; q++) gp *= r;
                sh_scal = alpha * (gp / SCAD_Af) + (1.0f - alpha) * (gd / SCAD_Af);
            }
            __syncthreads();
        }
        // -- prop phase: wave per row, lane = channel, y from LDS --
        {
            float lamc = sh_scal;
            int deg = rowcnt[i];
            float acc = 0.0f, wsum = 0.0f;
            for (int base = 0; base < deg; base += 64) {
                int m = deg - base; if (m > 64) m = 64;
                int   jl = (c < m) ? colIdx[i * MAXD + base + c] : 0;
                float yl = (c < m) ? y_loc[w][base + c] : 9.0f;
                float il = (c < m) ? isD[jl] : 0.0f;
                int tt = 0;
                for (; tt + 4 <= m; tt += 4) {
                    int j0 = __shfl(jl, tt, 64),     j1 = __shfl(jl, tt + 1, 64);
                    int j2 = __shfl(jl, tt + 2, 64), j3 = __shfl(jl, tt + 3, 64);
                    float f0 = fin[(size_t)j0 * 64 + c], f1 = fin[(size_t)j1 * 64 + c];
                    float f2 = fin[(size_t)j2 * 64 + c], f3 = fin[(size_t)j3 * 64 + c];
                    float s0 = scad_w(__shfl(yl, tt, 64),     lamc);
                    float s1 = scad_w(__shfl(yl, tt + 1, 64), lamc);
                    float s2 = scad_w(__shfl(yl, tt + 2, 64), lamc);
                    float s3 = scad_w(__shfl(yl, tt + 3, 64), lamc);
                    wsum += s0 + s1 + s2 + s3;
                    acc += s0 * __shfl(il, tt, 64) * f0 + s1 * __shfl(il, tt + 1, 64) * f1
                         + s2 * __shfl(il, tt + 2, 64) * f2 + s3 * __shfl(il, tt + 3, 64) * f3;
                }
                for (; tt < m; tt++) {
                    int   j = __shfl(jl, tt, 64);
                    float y = __shfl(yl, tt, 64);
                    float wq = scad_w(y, lamc);
                    wsum += wq;
                    acc += wq * __shfl(il, tt, 64) * fin[(size_t)j * 64 + c];
                }
            }
            float Q = wsum / D[i] + lam;
            float fo = (isD[i] * acc + lam * F0[(size_t)i * 64 + c]) / Q;
            fout[(size_t)i * 64 + c] = fo;
            float fn = fo * isD[i];
            float s2n = fn * fn;
            for (int off = 32; off; off >>= 1) s2n += __shfl_xor(s2n, off, 64);
            Fu[(size_t)i * 64 + c] = fn / fmaxf(sqrtf(s2n), EPSf);
        }
        grid.sync();
        fin = fout;
    }
}

// ===========================================================================
// Fallback path (round-9 structure, NBINS 2048, global y_e) — used if the
// cooperative launch is unavailable / rejected by the occupancy gate.
// ===========================================================================
__global__ __launch_bounds__(256)
void k_init(const float* __restrict__ A, const float* __restrict__ X,
            const float* __restrict__ W1, float* __restrict__ part,
            int* __restrict__ colIdx, int* __restrict__ rowcnt,
            float* __restrict__ D, float* __restrict__ isD,
            unsigned int* __restrict__ hist01) {
    __shared__ float As[16][68];
    __shared__ float Bs[16][64];
    __shared__ int cnt4[4];
    int tid = threadIdx.x;
    if (blockIdx.x < 1024) {
        int blk = blockIdx.x;
        int bx = blk & 3, by = (blk >> 2) & 63, bz = blk >> 8;
        int tx = tid & 15, ty = tid >> 4;
        int bm = by * 64, bn = bx * 64;
        int kbeg = bz * (IN_DIM / KSPLIT);
        float acc[4][4] = {};
        for (int k0 = kbeg; k0 < kbeg + IN_DIM / KSPLIT; k0 += 16) {
            {
                int r = tid >> 2, kv = tid & 3;
                float4 v = *(const float4*)(X + (size_t)(bm + r) * IN_DIM + k0 + kv * 4);
                As[kv * 4 + 0][r] = v.x;
                As[kv * 4 + 1][r] = v.y;
                As[kv * 4 + 2][r] = v.z;
                As[kv * 4 + 3][r] = v.w;
            }
            {
                int kk = tid >> 4, nv = tid & 15;
                *(float4*)&Bs[kk][nv * 4] =
                    *(const float4*)(W1 + (size_t)(k0 + kk) * H_DIM + bn + nv * 4);
            }
            __syncthreads();
#pragma unroll
            for (int kk = 0; kk < 16; kk++) {
                float a[4], b[4];
#pragma unroll
                for (int u = 0; u < 4; u++) { a[u] = As[kk][ty * 4 + u]; b[u] = Bs[kk][tx * 4 + u]; }
#pragma unroll
                for (int u = 0; u < 4; u++)
#pragma unroll
                    for (int v = 0; v < 4; v++) acc[u][v] += a[u] * b[v];
            }
            __syncthreads();
        }
        float* Cm = part + (size_t)bz * N_NODES * H_DIM;
#pragma unroll
        for (int u = 0; u < 4; u++) {
            int m = bm + ty * 4 + u;
#pragma unroll
            for (int v = 0; v < 4; v++)
                Cm[(size_t)m * H_DIM + bn + tx * 4 + v] = acc[u][v];
        }
    } else {
        int bb = blockIdx.x - 1024;
        int gid2 = bb * 256 + tid;
        if (gid2 < 2 * NBINS) hist01[gid2] = 0u;
        int w = tid >> 6, lane = tid & 63;
        int i = bb * 4 + w;
        if (lane == 0) cnt4[w] = 0;
        __syncthreads();
        const float4* row4 = (const float4*)(A + (size_t)i * N_NODES);
        int* ci = colIdx + i * MAXD;
        for (int v = lane; v < N_NODES / 4; v += 64) {
            float4 x = row4[v];
            int j0 = v * 4;
            if (x.x != 0.0f) { int p = atomicAdd(&cnt4[w], 1); ci[p] = j0; }
            if (x.y != 0.0f) { int p = atomicAdd(&cnt4[w], 1); ci[p] = j0 + 1; }
            if (x.z != 0.0f) { int p = atomicAdd(&cnt4[w], 1); ci[p] = j0 + 2; }
            if (x.w != 0.0f) { int p = atomicAdd(&cnt4[w], 1); ci[p] = j0 + 3; }
        }
        __syncthreads();
        if (lane == 0) {
            int t = cnt4[w];
            rowcnt[i] = t;
            float d = (float)t + 1.0f;
            D[i] = d;
            isD[i] = 1.0f / sqrtf(d);
        }
    }
}

__global__ __launch_bounds__(256)
void k_mlp2(const float* __restrict__ part, const float* __restrict__ b1,
            const float* __restrict__ W2, const float* __restrict__ b2,
            const int* __restrict__ rowcnt, const float* __restrict__ isD,
            float* __restrict__ F0, float* __restrict__ Fu, int* __restrict__ nE) {
    __shared__ float sh_h[4][H_DIM];
    int tid = threadIdx.x;
    if (blockIdx.x == 0) {
        __shared__ unsigned int ps[256];
        unsigned int s = 0;
        for (int q = tid; q < N_NODES; q += 256) s += (unsigned int)rowcnt[q];
        ps[tid] = s;
        __syncthreads();
        for (int off = 128; off; off >>= 1) {
            if (tid < off) ps[tid] += ps[tid + off];
            __syncthreads();
        }
        if (tid == 0) nE[0] = (int)ps[0];
    }
    int w = tid >> 6, lane = tid & 63;
    int i = blockIdx.x * 4 + w;
    const size_t tot = (size_t)N_NODES * H_DIM;
    const float* p0 = part + (size_t)i * H_DIM;
#pragma unroll
    for (int q = 0; q < 4; q++) {
        int k = q * 64 + lane;
        float s = p0[k] + p0[tot + k] + p0[2 * tot + k] + p0[3 * tot + k] + b1[k];
        sh_h[w][k] = fmaxf(s, 0.0f);
    }
    const float* W2c = W2 + lane;
    float a0 = 0, a1 = 0, a2 = 0, a3 = 0;
#pragma unroll 8
    for (int k = 0; k < H_DIM; k += 4) {
        a0 += sh_h[w][k + 0] * W2c[(k + 0) * OUT_DIM];
        a1 += sh_h[w][k + 1] * W2c[(k + 1) * OUT_DIM];
        a2 += sh_h[w][k + 2] * W2c[(k + 2) * OUT_DIM];
        a3 += sh_h[w][k + 3] * W2c[(k + 3) * OUT_DIM];
    }
    float f0 = (a0 + a1) + (a2 + a3) + b2[lane];
    F0[(size_t)i * 64 + lane] = f0;
    float fn = f0 * isD[i];
    float s2 = fn * fn;
    for (int off = 32; off; off >>= 1) s2 += __shfl_xor(s2, off, 64);
    Fu[(size_t)i * 64 + lane] = fn / fmaxf(sqrtf(s2), EPSf);
}

__global__ __launch_bounds__(256)
void k_edgehist(const float* __restrict__ Fu, const int* __restrict__ rowcnt,
                const int* __restrict__ colIdx, float* __restrict__ y_e,
                unsigned int* __restrict__ histK) {
    __shared__ unsigned int hl[NBINS];
    for (int b = threadIdx.x; b < NBINS; b += 256) hl[b] = 0u;
    __syncthreads();
    int gid = blockIdx.x * 256 + threadIdx.x;
    int ri = gid >> 6;
    int lane = threadIdx.x & 63;
    int eg = lane >> 2, el = lane & 3;
    int deg = rowcnt[ri];
    const float4* Fu4 = (const float4*)Fu;
    float4 fi0 = Fu4[ri * 16 + el * 4 + 0];
    float4 fi1 = Fu4[ri * 16 + el * 4 + 1];
    float4 fi2 = Fu4[ri * 16 + el * 4 + 2];
    float4 fi3 = Fu4[ri * 16 + el * 4 + 3];
    for (int base = 0; base < deg; base += 16) {
        int e = base + eg;
        bool act = e < deg;
        int j = act ? colIdx[ri * MAXD + e] : ri;
        float4 a0 = Fu4[(size_t)j * 16 + el * 4 + 0];
        float4 a1 = Fu4[(size_t)j * 16 + el * 4 + 1];
        float4 a2 = Fu4[(size_t)j * 16 + el * 4 + 2];
        float4 a3 = Fu4[(size_t)j * 16 + el * 4 + 3];
        float s = fi0.x * a0.x + fi0.y * a0.y + fi0.z * a0.z + fi0.w * a0.w
                + fi1.x * a1.x + fi1.y * a1.y + fi1.z * a1.z + fi1.w * a1.w
                + fi2.x * a2.x + fi2.y * a2.y + fi2.z * a2.z + fi2.w * a2.w
                + fi3.x * a3.x + fi3.y * a3.y + fi3.z * a3.z + fi3.w * a3.w;
        s += __shfl_xor(s, 1, 64);
        s += __shfl_xor(s, 2, 64);
        if (act && el == 0) {
            float y = 1.0f - s;
            y = fminf(fmaxf(y, 0.0f), 2.0f);
            y_e[ri * MAXD + e] = y;
            int bin = (int)(y * (NBINS * 0.5f));
            if (bin > NBINS - 1) bin = NBINS - 1;
            atomicAdd(&hl[bin], 1u);
        }
    }
    __syncthreads();
    for (int b = threadIdx.x; b < NBINS; b += 256) {
        unsigned int v = hl[b];
        if (v) atomicAdd(&histK[b], v);
    }
}

__global__ __launch_bounds__(256)
void k_propq(const unsigned int* __restrict__ histK, unsigned int* __restrict__ histNext,
             const int* __restrict__ nEp, const int* __restrict__ rowcnt,
             const int* __restrict__ colIdx, const float* __restrict__ y_e,
             const float* __restrict__ Fc, const float* __restrict__ F0,
             const float* __restrict__ D, const float* __restrict__ isD,
             const float* __restrict__ lg0, const float* __restrict__ rdec,
             const float* __restrict__ ralpha, int kiter,
             float* __restrict__ Fout, float* __restrict__ FuNext) {
    __shared__ unsigned int psum[256];
    __shared__ float vv[2];
    __shared__ float sh_scal;
    int tid = threadIdx.x;
    int gid = blockIdx.x * 256 + tid;
    if (gid < NBINS) histNext[gid] = 0u;
    {
        unsigned int cnt[8];
        const uint4* h4 = (const uint4*)histK;
        unsigned int s = 0;
#pragma unroll
        for (int q = 0; q < 2; q++) {
            uint4 v = h4[tid * 2 + q];
            cnt[q * 4 + 0] = v.x; cnt[q * 4 + 1] = v.y;
            cnt[q * 4 + 2] = v.z; cnt[q * 4 + 3] = v.w;
            s += v.x + v.y + v.z + v.w;
        }
        psum[tid] = s;
        __syncthreads();
        for (int off = 1; off < 256; off <<= 1) {
            unsigned int x = 0;
            if (tid >= off) x = psum[tid - off];
            __syncthreads();
            psum[tid] += x;
            __syncthreads();
        }
        int nE = nEp[0];
        double h = 0.75 * (double)(nE - 1);
        long long i0 = (long long)h;
        float frac = (float)(h - (double)i0);
        unsigned int r0 = (unsigned int)i0, r1 = (unsigned int)(i0 + 1);
        unsigned int cum = (tid == 0) ? 0u : psum[tid - 1];
#pragma unroll
        for (int b = 0; b < 8; b++) {
            unsigned int cn = cnt[b];
            unsigned int lo = cum;
            cum += cn;
            if (cn) {
                float v = ((float)(tid * 8 + b) + 0.5f) * (2.0f / (float)NBINS);
                if (lo <= r0 && r0 < cum) vv[0] = v;
                if (lo <= r1 && r1 < cum) vv[1] = v;
            }
        }
        __syncthreads();
        if (tid == 0) {
            float gd = vv[0] + frac * (vv[1] - vv[0]);
            gd = fmaxf(gd, EPSf);
            float alpha = 1.0f / (1.0f + expf(-ralpha[0]));
            float g0 = expf(lg0[0]);
            float r = 1.0f / (1.0f + expf(-rdec[0]));
            float gp = g0;
            for (int q = 0; q < kiter; q++) gp *= r;
            sh_scal = alpha * (gp / SCAD_Af) + (1.0f - alpha) * (gd / SCAD_Af);
        }
        __syncthreads();
    }
    float lamc = sh_scal;
    const float lam = (float)(1.0 / 0.9 - 1.0);
    int i = gid >> 6, c = gid & 63;
    int deg = rowcnt[i];
    float acc = 0.0f, wsum = 0.0f;
    for (int base = 0; base < deg; base += 64) {
        int m = deg - base; if (m > 64) m = 64;
        int   jl = (c < m) ? colIdx[i * MAXD + base + c] : 0;
        float yl = (c < m) ? y_e[i * MAXD + base + c] : 9.0f;
        float il = (c < m) ? isD[jl] : 0.0f;
        int tt = 0;
        for (; tt + 4 <= m; tt += 4) {
            int j0 = __shfl(jl, tt, 64),     j1 = __shfl(jl, tt + 1, 64);
            int j2 = __shfl(jl, tt + 2, 64), j3 = __shfl(jl, tt + 3, 64);
            float f0 = Fc[(size_t)j0 * 64 + c], f1 = Fc[(size_t)j1 * 64 + c];
            float f2 = Fc[(size_t)j2 * 64 + c], f3 = Fc[(size_t)j3 * 64 + c];
            float s0 = scad_w(__shfl(yl, tt, 64),     lamc);
            float s1 = scad_w(__shfl(yl, tt + 1, 64), lamc);
            float s2 = scad_w(__shfl(yl, tt + 2, 64), lamc);
            float s3 = scad_w(__shfl(yl, tt + 3, 64), lamc);
            wsum += s0 + s1 + s2 + s3;
            acc += s0 * __shfl(il, tt, 64) * f0 + s1 * __shfl(il, tt + 1, 64) * f1
                 + s2 * __shfl(il, tt + 2, 64) * f2 + s3 * __shfl(il, tt + 3, 64) * f3;
        }
        for (; tt < m; tt++) {
            int   j = __shfl(jl, tt, 64);
            float y = __shfl(yl, tt, 64);
            float wq = scad_w(y, lamc);
            wsum += wq;
            acc += wq * __shfl(il, tt, 64) * Fc[(size_t)j * 64 + c];
        }
    }
    float Q = wsum / D[i] + lam;
    float fo = (isD[i] * acc + lam * F0[(size_t)i * 64 + c]) / Q;
    Fout[(size_t)i * 64 + c] = fo;
    float fn = fo * isD[i];
    float s2n = fn * fn;
    for (int off = 32; off; off >>= 1) s2n += __shfl_xor(s2n, off, 64);
    FuNext[(size_t)i * 64 + c] = fn / fmaxf(sqrtf(s2n), EPSf);
}

// ---------------------------------------------------------------------------
extern "C" void kernel_launch(void* const* d_in, const int* in_sizes, int n_in,
                              void* d_out, int out_size, void* d_ws, size_t ws_size,
                              hipStream_t stream) {
    const float* A      = (const float*)d_in[0];
    const float* X      = (const float*)d_in[1];
    const float* W1     = (const float*)d_in[2];
    const float* b1     = (const float*)d_in[3];
    const float* W2     = (const float*)d_in[4];
    const float* b2     = (const float*)d_in[5];
    const float* lg0    = (const float*)d_in[6];
    const float* rdec   = (const float*)d_in[7];
    const float* ralpha = (const float*)d_in[8];
    float* outp = (float*)d_out;

    char* w = (char*)d_ws;
    size_t off = 0;
    auto carve = [&](size_t bytes) -> char* {
        char* p = w + off;
        off += (bytes + 255) & ~(size_t)255;
        return p;
    };
    int*      colIdx = (int*)carve((size_t)N_NODES * MAXD * 4);
    float*    y_e    = (float*)carve((size_t)N_NODES * MAXD * 4);       // fallback only
    float*    part   = (float*)carve((size_t)KSPLIT * N_NODES * H_DIM * 4);
    int*      rowcnt = (int*)carve(N_NODES * 4);
    float*    D      = (float*)carve(N_NODES * 4);
    float*    isD    = (float*)carve(N_NODES * 4);
    float*    Fu     = (float*)carve((size_t)N_NODES * 64 * 4);
    float*    F0     = (float*)carve((size_t)N_NODES * 64 * 4);
    float*    FcA    = (float*)carve((size_t)N_NODES * 64 * 4);
    float*    FcB    = (float*)carve((size_t)N_NODES * 64 * 4);
    unsigned* hist01 = (unsigned*)carve(2 * NBINS * 4);
    int*      nE     = (int*)carve(256);

    // Deterministic, capture-safe gate for the cooperative path.
    int coopAttr = 0, numCU = 0, maxPerCU = 0;
    (void)hipDeviceGetAttribute(&coopAttr, hipDeviceAttributeCooperativeLaunch, 0);
    (void)hipDeviceGetAttribute(&numCU, hipDeviceAttributeMultiprocessorCount, 0);
    (void)hipOccupancyMaxActiveBlocksPerMultiprocessor(&maxPerCU, k_mega, 256, 0);
    bool useCoop = (coopAttr != 0) && ((long)maxPerCU * (long)numCU >= 1024);

    if (useCoop) {
        void* args[] = {
            (void*)&A, (void*)&X, (void*)&W1, (void*)&b1, (void*)&W2, (void*)&b2,
            (void*)&lg0, (void*)&rdec, (void*)&ralpha,
            (void*)&colIdx, (void*)&rowcnt, (void*)&D, (void*)&isD,
            (void*)&Fu, (void*)&part, (void*)&F0,
            (void*)&FcA, (void*)&FcB, (void*)&outp, (void*)&hist01,
        };
        hipError_t e = hipLaunchCooperativeKernel((void*)k_mega, dim3(1024), dim3(256),
                                                  args, 0, stream);
        if (e == hipSuccess) return;
        (void)hipGetLastError();   // clear sticky error; fall through to fallback
    }

    // Fallback: proven 10-kernel path.
    k_init<<<dim3(2048), dim3(256), 0, stream>>>(A, X, W1, part, colIdx, rowcnt, D, isD, hist01);
    k_mlp2<<<dim3(1024), dim3(256), 0, stream>>>(part, b1, W2, b2, rowcnt, isD, F0, Fu, nE);
    const float* fin = F0;
    float* fouts[4] = {FcA, FcB, FcA, outp};
    for (int k = 0; k < 4; k++) {
        unsigned* histK    = hist01 + (k & 1) * NBINS;
        unsigned* histNext = hist01 + ((k + 1) & 1) * NBINS;
        k_edgehist<<<dim3(1024), dim3(256), 0, stream>>>(Fu, rowcnt, colIdx, y_e, histK);
        k_propq<<<dim3(1024), dim3(256), 0, stream>>>(histK, histNext, nE, rowcnt, colIdx,
                                                      y_e, fin, F0, D, isD, lg0, rdec,
                                                      ralpha, k, fouts[k], Fu);
        fin = fouts[k];
    }
}